// Round 1
// baseline (761.272 us; speedup 1.0000x reference)
//
#include <hip/hip_runtime.h>

// ---------------------------------------------------------------------------
// Types / helpers
// ---------------------------------------------------------------------------
typedef __attribute__((ext_vector_type(8))) short short8;     // 8 bf16 (4 VGPR)
typedef __attribute__((ext_vector_type(4))) float f32x4;      // mfma C/D frag
typedef __attribute__((ext_vector_type(4))) float float4v;
typedef __attribute__((ext_vector_type(4))) unsigned short ushort4v;

#define MFMA16(a, b, c) __builtin_amdgcn_mfma_f32_16x16x32_bf16((a), (b), (c), 0, 0, 0)
#define GLOAD_LDS16(g, s)                                                         \
  __builtin_amdgcn_global_load_lds((const __attribute__((address_space(1))) void*)(g), \
                                   (__attribute__((address_space(3))) void*)(s), 16, 0, 0)

__device__ __forceinline__ unsigned short f2bf(float f) {
  unsigned u = __builtin_bit_cast(unsigned, f);
  u += 0x7fffu + ((u >> 16) & 1u);   // round-to-nearest-even
  return (unsigned short)(u >> 16);
}

// ---------------------------------------------------------------------------
// fp32 -> bf16 convert (vectorized, grid-stride)
// ---------------------------------------------------------------------------
__global__ __launch_bounds__(256) void cvt_bf16(const float* __restrict__ src,
                                                unsigned short* __restrict__ dst, int n) {
  int i = (blockIdx.x * 256 + threadIdx.x) * 4;
  int stride = gridDim.x * 256 * 4;
  for (; i < n; i += stride) {
    float4v v = *(const float4v*)(src + i);
    ushort4v o;
    o.x = f2bf(v.x); o.y = f2bf(v.y); o.z = f2bf(v.z); o.w = f2bf(v.w);
    *(ushort4v*)(dst + i) = o;
  }
}

// ---------------------------------------------------------------------------
// GEMM: C[M][N] = act(A[M][K] @ B[N][K]^T + bias[N]) (+ residual)
// A,B bf16 row-major (K contiguous).  128x128 tile, BK=32, 4 waves (2x2 of 64x64)
// ---------------------------------------------------------------------------
template <bool RELU, bool RES, bool OUTF, bool OUTB>
__global__ __launch_bounds__(256) void gemm_bt(const unsigned short* __restrict__ A,
                                               const unsigned short* __restrict__ B,
                                               const float* __restrict__ bias,
                                               const float* __restrict__ res,
                                               float* __restrict__ outF,
                                               unsigned short* __restrict__ outB,
                                               int M, int N, int K) {
  __shared__ __align__(16) unsigned short As[128 * 32];
  __shared__ __align__(16) unsigned short Bs[128 * 32];
  const int tid = threadIdx.x;
  const int w = tid >> 6, lane = tid & 63;
  const int l15 = lane & 15, l4 = lane >> 4;
  const int rowBase = blockIdx.y * 128, colBase = blockIdx.x * 128;
  const int wm = w >> 1, wn = w & 1;

  f32x4 acc[4][4] = {};

  const int c0 = w * 64 + lane;       // chunk ids for staging (8 bf16 = 16B per chunk)
  const int c1 = 256 + c0;

  for (int k0 = 0; k0 < K; k0 += 32) {
    // stage A,B tiles: 128 rows x 32 k, linear LDS layout (global_load_lds: lane*16B)
    const unsigned short* ga0 = A + (size_t)(rowBase + (c0 >> 2)) * K + k0 + ((c0 & 3) << 3);
    const unsigned short* ga1 = A + (size_t)(rowBase + (c1 >> 2)) * K + k0 + ((c1 & 3) << 3);
    GLOAD_LDS16(ga0, As + w * 512);
    GLOAD_LDS16(ga1, As + 2048 + w * 512);
    const unsigned short* gb0 = B + (size_t)(colBase + (c0 >> 2)) * K + k0 + ((c0 & 3) << 3);
    const unsigned short* gb1 = B + (size_t)(colBase + (c1 >> 2)) * K + k0 + ((c1 & 3) << 3);
    GLOAD_LDS16(gb0, Bs + w * 512);
    GLOAD_LDS16(gb1, Bs + 2048 + w * 512);
    __syncthreads();

    short8 af[4], bf[4];
#pragma unroll
    for (int f = 0; f < 4; ++f) {
      af[f] = *(const short8*)(As + (wm * 64 + f * 16 + l15) * 32 + l4 * 8);
      bf[f] = *(const short8*)(Bs + (wn * 64 + f * 16 + l15) * 32 + l4 * 8);
    }
#pragma unroll
    for (int i = 0; i < 4; ++i)
#pragma unroll
      for (int j = 0; j < 4; ++j)
        acc[i][j] = MFMA16(af[i], bf[j], acc[i][j]);
    __syncthreads();
  }

  // epilogue: D[row=(l4*4+e)][col=l15] per 16x16 frag
#pragma unroll
  for (int i = 0; i < 4; ++i) {
    const int row0 = rowBase + wm * 64 + i * 16 + l4 * 4;
#pragma unroll
    for (int j = 0; j < 4; ++j) {
      const int col = colBase + wn * 64 + j * 16 + l15;
      const float bv = bias[col];
#pragma unroll
      for (int e = 0; e < 4; ++e) {
        const int row = row0 + e;
        float v = acc[i][j][e] + bv;
        if constexpr (RELU) v = fmaxf(v, 0.f);
        if constexpr (RES) v += res[(size_t)row * N + col];
        if constexpr (OUTF) outF[(size_t)row * N + col] = v;
        if constexpr (OUTB) outB[(size_t)row * N + col] = f2bf(v);
      }
    }
  }
}

// ---------------------------------------------------------------------------
// Flash attention fwd: qkv [N][3072] bf16 -> out [N][1024] bf16
// 16 heads, hd=64.  Block: 4 waves; wave handles 16 q-rows.  KBLK=64.
// ---------------------------------------------------------------------------
__global__ __launch_bounds__(256) void flash_attn(const unsigned short* __restrict__ qkv,
                                                  unsigned short* __restrict__ out, int Nseq) {
  __shared__ __align__(16) unsigned short Vt[64][72];      // V^T tile, padded
  __shared__ __align__(16) unsigned short Pl[4][16][72];   // per-wave P tile, padded
  const int tid = threadIdx.x;
  const int w = tid >> 6, lane = tid & 63;
  const int l15 = lane & 15, l4 = lane >> 4;
  const int head = blockIdx.y;
  const int q0 = blockIdx.x * 64 + w * 16;
  const int LDQ = 3072;
  const unsigned short* Qp = qkv + head * 64;
  const unsigned short* Kp = qkv + 1024 + head * 64;
  const unsigned short* Vp = qkv + 2048 + head * 64;

  short8 qf[2];
#pragma unroll
  for (int kb = 0; kb < 2; ++kb)
    qf[kb] = *(const short8*)(Qp + (size_t)(q0 + l15) * LDQ + kb * 32 + l4 * 8);

  float m[4], ls[4];
  f32x4 O[4] = {};
#pragma unroll
  for (int j = 0; j < 4; ++j) { m[j] = -1e30f; ls[j] = 0.f; }

  for (int kt = 0; kt < Nseq; kt += 64) {
    // stage V tile transposed: Vt[d][k]
#pragma unroll
    for (int i = 0; i < 2; ++i) {
      const int c = tid * 2 + i;             // 0..511
      const int kr = c >> 3, dc = (c & 7) * 8;
      short8 v = *(const short8*)(Vp + (size_t)(kt + kr) * LDQ + dc);
#pragma unroll
      for (int e = 0; e < 8; ++e) Vt[dc + e][kr] = (unsigned short)v[e];
    }
    __syncthreads();

    // S = Q K^T for 4 16x16 tiles (K-frags straight from global; L2-resident)
    f32x4 S[4] = {};
#pragma unroll
    for (int st = 0; st < 4; ++st) {
      const unsigned short* kr = Kp + (size_t)(kt + st * 16 + l15) * LDQ + l4 * 8;
      S[st] = MFMA16(qf[0], *(const short8*)(kr), S[st]);
      S[st] = MFMA16(qf[1], *(const short8*)(kr + 32), S[st]);
    }

    // online softmax (rows = l4*4+j, cols across 16 lanes x 4 tiles)
    float rmax[4];
#pragma unroll
    for (int j = 0; j < 4; ++j)
      rmax[j] = fmaxf(fmaxf(S[0][j], S[1][j]), fmaxf(S[2][j], S[3][j])) * 0.125f;
#pragma unroll
    for (int off = 1; off < 16; off <<= 1)
#pragma unroll
      for (int j = 0; j < 4; ++j) rmax[j] = fmaxf(rmax[j], __shfl_xor(rmax[j], off));

    float fac[4], rs[4];
#pragma unroll
    for (int j = 0; j < 4; ++j) {
      const float mn = fmaxf(m[j], rmax[j]);
      fac[j] = __expf(m[j] - mn);
      m[j] = mn;
      rs[j] = 0.f;
    }
#pragma unroll
    for (int st = 0; st < 4; ++st)
#pragma unroll
      for (int j = 0; j < 4; ++j) {
        const float p = __expf(S[st][j] * 0.125f - m[j]);
        rs[j] += p;
        Pl[w][l4 * 4 + j][st * 16 + l15] = f2bf(p);
      }
#pragma unroll
    for (int off = 1; off < 16; off <<= 1)
#pragma unroll
      for (int j = 0; j < 4; ++j) rs[j] += __shfl_xor(rs[j], off);
#pragma unroll
    for (int j = 0; j < 4; ++j) ls[j] = ls[j] * fac[j] + rs[j];
#pragma unroll
    for (int fd = 0; fd < 4; ++fd)
#pragma unroll
      for (int j = 0; j < 4; ++j) O[fd][j] *= fac[j];

    // O += P @ V
#pragma unroll
    for (int kb = 0; kb < 2; ++kb) {
      short8 pf = *(const short8*)(&Pl[w][l15][kb * 32 + l4 * 8]);
#pragma unroll
      for (int fd = 0; fd < 4; ++fd) {
        short8 vf = *(const short8*)(&Vt[fd * 16 + l15][kb * 32 + l4 * 8]);
        O[fd] = MFMA16(pf, vf, O[fd]);
      }
    }
    __syncthreads();
  }

  // normalize + store
#pragma unroll
  for (int fd = 0; fd < 4; ++fd)
#pragma unroll
    for (int j = 0; j < 4; ++j) {
      const int row = q0 + l4 * 4 + j;
      const int col = head * 64 + fd * 16 + l15;
      out[(size_t)row * 1024 + col] = f2bf(O[fd][j] / ls[j]);
    }
}

// ---------------------------------------------------------------------------
// Row LayerNorm (two-pass, fp32).  One block (256 thr) per row.
// ---------------------------------------------------------------------------
template <int D>
__global__ __launch_bounds__(256) void ln_rows(const float* __restrict__ src,
                                               const float* __restrict__ gw,
                                               const float* __restrict__ bw,
                                               float* __restrict__ outF,
                                               unsigned short* __restrict__ outB) {
  __shared__ float red[4];
  const int row = blockIdx.x;
  const int tid = threadIdx.x, w = tid >> 6;
  constexpr int PT = D / 256;
  const float* r = src + (size_t)row * D;
  float v[PT];
  float s = 0.f;
#pragma unroll
  for (int i = 0; i < PT; ++i) { v[i] = r[tid + i * 256]; s += v[i]; }
#pragma unroll
  for (int off = 32; off; off >>= 1) s += __shfl_down(s, off);
  if ((tid & 63) == 0) red[w] = s;
  __syncthreads();
  const float mean = (red[0] + red[1] + red[2] + red[3]) / D;
  __syncthreads();
  float q = 0.f;
#pragma unroll
  for (int i = 0; i < PT; ++i) { const float d = v[i] - mean; q += d * d; }
#pragma unroll
  for (int off = 32; off; off >>= 1) q += __shfl_down(q, off);
  if ((tid & 63) == 0) red[w] = q;
  __syncthreads();
  const float rstd = rsqrtf((red[0] + red[1] + red[2] + red[3]) / D + 1e-5f);
#pragma unroll
  for (int i = 0; i < PT; ++i) {
    const int c = tid + i * 256;
    const float o = (v[i] - mean) * rstd * gw[c] + bw[c];
    outF[(size_t)row * D + c] = o;
    if (outB) outB[(size_t)row * D + c] = f2bf(o);
  }
}

// ---------------------------------------------------------------------------
// Orchestration
// ---------------------------------------------------------------------------
extern "C" void kernel_launch(void* const* d_in, const int* in_sizes, int n_in,
                              void* d_out, int out_size, void* d_ws, size_t ws_size,
                              hipStream_t stream) {
  const int N = 2048, D_IN = 512, H = 1024, D_OUT = 256, NL = 4;
  const float* x    = (const float*)d_in[0];
  const float* W1   = (const float*)d_in[1];
  const float* b1   = (const float*)d_in[2];
  const float* Wqkv = (const float*)d_in[3];
  const float* bqkv = (const float*)d_in[4];
  const float* Wo   = (const float*)d_in[5];
  const float* bo   = (const float*)d_in[6];
  const float* lng  = (const float*)d_in[7];
  const float* lnb  = (const float*)d_in[8];
  const float* W2   = (const float*)d_in[9];
  const float* b2   = (const float*)d_in[10];
  const float* gout = (const float*)d_in[11];
  const float* bout = (const float*)d_in[12];
  float* out = (float*)d_out;

  char* ws = (char*)d_ws;
  auto alloc = [&](size_t bytes) -> char* {
    char* p = ws;
    ws += (bytes + 255) & ~(size_t)255;
    return p;
  };
  unsigned short* xb    = (unsigned short*)alloc((size_t)N * D_IN * 2);
  unsigned short* W1b   = (unsigned short*)alloc((size_t)H * D_IN * 2);
  unsigned short* Wqkvb = (unsigned short*)alloc((size_t)NL * 3 * H * H * 2);
  unsigned short* Wob   = (unsigned short*)alloc((size_t)NL * H * H * 2);
  unsigned short* W2b   = (unsigned short*)alloc((size_t)D_OUT * H * 2);
  unsigned short* hb    = (unsigned short*)alloc((size_t)N * H * 2);
  unsigned short* qkvb  = (unsigned short*)alloc((size_t)N * 3 * H * 2);
  unsigned short* aob   = (unsigned short*)alloc((size_t)N * H * 2);
  float* hf = (float*)alloc((size_t)N * H * 4);
  float* af = (float*)alloc((size_t)N * H * 4);
  float* yf = (float*)alloc((size_t)N * D_OUT * 4);

  auto cvt = [&](const float* s, unsigned short* d, int n) {
    int blocks = (n / 4 + 255) / 256;
    if (blocks > 2048) blocks = 2048;
    cvt_bf16<<<blocks, 256, 0, stream>>>(s, d, n);
  };
  cvt(x, xb, N * D_IN);
  cvt(W1, W1b, H * D_IN);
  cvt(Wqkv, Wqkvb, NL * 3 * H * H);
  cvt(Wo, Wob, NL * H * H);
  cvt(W2, W2b, D_OUT * H);

  // FC1: h = relu(x @ W1^T + b1) -> hf, hb
  gemm_bt<true, false, true, true><<<dim3(H / 128, N / 128), 256, 0, stream>>>(
      xb, W1b, b1, nullptr, hf, hb, N, H, D_IN);

  for (int l = 0; l < NL; ++l) {
    // qkv = h @ Wqkv^T + bqkv
    gemm_bt<false, false, false, true><<<dim3(3 * H / 128, N / 128), 256, 0, stream>>>(
        hb, Wqkvb + (size_t)l * 3 * H * H, bqkv + (size_t)l * 3 * H, nullptr, nullptr, qkvb,
        N, 3 * H, H);
    // attention
    flash_attn<<<dim3(N / 64, 16), 256, 0, stream>>>(qkvb, aob, N);
    // o = attn @ Wo^T + bo + h  -> af (fp32)
    gemm_bt<false, true, true, false><<<dim3(H / 128, N / 128), 256, 0, stream>>>(
        aob, Wob + (size_t)l * H * H, bo + (size_t)l * H, hf, af, nullptr, N, H, H);
    // h = LN(af) -> hf, hb
    ln_rows<1024><<<N, 256, 0, stream>>>(af, lng + (size_t)l * H, lnb + (size_t)l * H, hf, hb);
  }

  // y = relu(h @ W2^T + b2) -> yf
  gemm_bt<true, false, true, false><<<dim3(D_OUT / 128, N / 128), 256, 0, stream>>>(
      hb, W2b, b2, nullptr, yf, nullptr, N, D_OUT, H);
  // out = LN(y)
  ln_rows<256><<<N, 256, 0, stream>>>(yf, gout, bout, out, nullptr);
}

// Round 2
// 538.007 us; speedup vs baseline: 1.4150x; 1.4150x over previous
//
#include <hip/hip_runtime.h>

// ---------------------------------------------------------------------------
// Types / helpers
// ---------------------------------------------------------------------------
typedef __attribute__((ext_vector_type(8))) short short8;     // 8 bf16 (4 VGPR)
typedef __attribute__((ext_vector_type(4))) float f32x4;      // mfma C/D frag
typedef __attribute__((ext_vector_type(4))) float float4v;
typedef __attribute__((ext_vector_type(4))) unsigned short ushort4v;

#define MFMA16(a, b, c) __builtin_amdgcn_mfma_f32_16x16x32_bf16((a), (b), (c), 0, 0, 0)
#define GLOAD_LDS16(g, s)                                                         \
  __builtin_amdgcn_global_load_lds((const __attribute__((address_space(1))) void*)(g), \
                                   (__attribute__((address_space(3))) void*)(s), 16, 0, 0)

__device__ __forceinline__ unsigned short f2bf(float f) {
  unsigned u = __builtin_bit_cast(unsigned, f);
  u += 0x7fffu + ((u >> 16) & 1u);   // round-to-nearest-even
  return (unsigned short)(u >> 16);
}

// ---------------------------------------------------------------------------
// fp32 -> bf16 convert (vectorized, grid-stride)
// ---------------------------------------------------------------------------
__global__ __launch_bounds__(256) void cvt_bf16(const float* __restrict__ src,
                                                unsigned short* __restrict__ dst, int n) {
  int i = (blockIdx.x * 256 + threadIdx.x) * 4;
  int stride = gridDim.x * 256 * 4;
  for (; i < n; i += stride) {
    float4v v = *(const float4v*)(src + i);
    ushort4v o;
    o.x = f2bf(v.x); o.y = f2bf(v.y); o.z = f2bf(v.z); o.w = f2bf(v.w);
    *(ushort4v*)(dst + i) = o;
  }
}

// ---------------------------------------------------------------------------
// GEMM: C[M][N] = act(A[M][K] @ B[N][K]^T + bias[N]) (+ residual)
// ---------------------------------------------------------------------------
template <bool RELU, bool RES, bool OUTF, bool OUTB>
__global__ __launch_bounds__(256) void gemm_bt(const unsigned short* __restrict__ A,
                                               const unsigned short* __restrict__ B,
                                               const float* __restrict__ bias,
                                               const float* __restrict__ res,
                                               float* __restrict__ outF,
                                               unsigned short* __restrict__ outB,
                                               int M, int N, int K) {
  __shared__ __align__(16) unsigned short As[128 * 32];
  __shared__ __align__(16) unsigned short Bs[128 * 32];
  const int tid = threadIdx.x;
  const int w = tid >> 6, lane = tid & 63;
  const int l15 = lane & 15, l4 = lane >> 4;
  const int rowBase = blockIdx.y * 128, colBase = blockIdx.x * 128;
  const int wm = w >> 1, wn = w & 1;

  f32x4 acc[4][4] = {};

  const int c0 = w * 64 + lane;
  const int c1 = 256 + c0;

  for (int k0 = 0; k0 < K; k0 += 32) {
    const unsigned short* ga0 = A + (size_t)(rowBase + (c0 >> 2)) * K + k0 + ((c0 & 3) << 3);
    const unsigned short* ga1 = A + (size_t)(rowBase + (c1 >> 2)) * K + k0 + ((c1 & 3) << 3);
    GLOAD_LDS16(ga0, As + w * 512);
    GLOAD_LDS16(ga1, As + 2048 + w * 512);
    const unsigned short* gb0 = B + (size_t)(colBase + (c0 >> 2)) * K + k0 + ((c0 & 3) << 3);
    const unsigned short* gb1 = B + (size_t)(colBase + (c1 >> 2)) * K + k0 + ((c1 & 3) << 3);
    GLOAD_LDS16(gb0, Bs + w * 512);
    GLOAD_LDS16(gb1, Bs + 2048 + w * 512);
    __syncthreads();

    short8 af[4], bf[4];
#pragma unroll
    for (int f = 0; f < 4; ++f) {
      af[f] = *(const short8*)(As + (wm * 64 + f * 16 + l15) * 32 + l4 * 8);
      bf[f] = *(const short8*)(Bs + (wn * 64 + f * 16 + l15) * 32 + l4 * 8);
    }
#pragma unroll
    for (int i = 0; i < 4; ++i)
#pragma unroll
      for (int j = 0; j < 4; ++j)
        acc[i][j] = MFMA16(af[i], bf[j], acc[i][j]);
    __syncthreads();
  }

#pragma unroll
  for (int i = 0; i < 4; ++i) {
    const int row0 = rowBase + wm * 64 + i * 16 + l4 * 4;
#pragma unroll
    for (int j = 0; j < 4; ++j) {
      const int col = colBase + wn * 64 + j * 16 + l15;
      const float bv = bias[col];
#pragma unroll
      for (int e = 0; e < 4; ++e) {
        const int row = row0 + e;
        float v = acc[i][j][e] + bv;
        if constexpr (RELU) v = fmaxf(v, 0.f);
        if constexpr (RES) v += res[(size_t)row * N + col];
        if constexpr (OUTF) outF[(size_t)row * N + col] = v;
        if constexpr (OUTB) outB[(size_t)row * N + col] = f2bf(v);
      }
    }
  }
}

// ---------------------------------------------------------------------------
// V transpose: vt[c][r] = qkv[r][2048+c], c in [0,1024), r in [0,N)
// ---------------------------------------------------------------------------
__global__ __launch_bounds__(256) void transpose_v(const unsigned short* __restrict__ qkv,
                                                   unsigned short* __restrict__ vt, int Nseq) {
  __shared__ unsigned short T[64][72];
  const int r0 = blockIdx.x * 64;   // k rows
  const int c0 = blockIdx.y * 64;   // v cols
  const int tid = threadIdx.x;
#pragma unroll
  for (int i = 0; i < 2; ++i) {
    int c = tid * 2 + i;
    int r = c >> 3, off = (c & 7) * 8;
    short8 v = *(const short8*)(qkv + (size_t)(r0 + r) * 3072 + 2048 + c0 + off);
    *(short8*)(&T[r][off]) = v;
  }
  __syncthreads();
#pragma unroll
  for (int i = 0; i < 2; ++i) {
    int c = tid * 2 + i;
    int orow = c >> 3, off = (c & 7) * 8;
    short8 v;
#pragma unroll
    for (int e = 0; e < 8; ++e) v[e] = T[off + e][orow];
    *(short8*)(vt + (size_t)(c0 + orow) * Nseq + r0 + off) = v;
  }
}

// ---------------------------------------------------------------------------
// Flash attention, split-K over keys (KSPLIT=2), swapped QK^T (S^T via mfma(K,Q)).
// Block: 4 waves, each 16 q-rows; stages K tile and Vt tile in padded LDS.
// Partials: Op[s][q][head*64+d] fp32 (un-normalized), Ml/Ll[s][head][q].
// ---------------------------------------------------------------------------
__global__ __launch_bounds__(256, 4) void flash_attn2(const unsigned short* __restrict__ qkv,
                                                      const unsigned short* __restrict__ vt,
                                                      float* __restrict__ Op0,
                                                      float* __restrict__ Op1,
                                                      float* __restrict__ Ml,
                                                      float* __restrict__ Ll,
                                                      int Nseq) {
  __shared__ __align__(16) unsigned short Ks[64][72];
  __shared__ __align__(16) unsigned short Vs[64][72];
  __shared__ __align__(16) unsigned short Pl[4][16][72];
  const int tid = threadIdx.x;
  const int w = tid >> 6, lane = tid & 63;
  const int l15 = lane & 15, l4 = lane >> 4;

  // 1D grid decode: all blocks of one head land on one XCD (round-robin heuristic)
  const int x = blockIdx.x;
  const int xcd = x & 7, slot = x >> 3;
  const int head = xcd + 8 * (slot >> 6);
  const int rem = slot & 63;
  const int s = rem >> 5;
  const int q0 = (rem & 31) * 64 + w * 16;

  const unsigned short* Qp = qkv + head * 64;
  const unsigned short* Kp = qkv + 1024 + head * 64;
  const unsigned short* Vtp = vt + (size_t)head * 64 * Nseq;

  short8 qf[2];
#pragma unroll
  for (int kb = 0; kb < 2; ++kb)
    qf[kb] = *(const short8*)(Qp + (size_t)(q0 + l15) * 3072 + kb * 32 + l4 * 8);

  float m = -1e30f, ls = 0.f;
  f32x4 O[4] = {};

  const int kt0 = s * (Nseq / 2);
  const int cA = tid, cB = tid + 256;          // staging chunk ids (row=c>>3, off=(c&7)*8)
  const int rA = cA >> 3, oA = (cA & 7) * 8;
  const int rB = cB >> 3, oB = (cB & 7) * 8;

  for (int kt = kt0; kt < kt0 + Nseq / 2; kt += 64) {
    // stage K[64][64] and Vt[64][64] tiles (vector loads, padded LDS writes)
    *(short8*)(&Ks[rA][oA]) = *(const short8*)(Kp + (size_t)(kt + rA) * 3072 + oA);
    *(short8*)(&Ks[rB][oB]) = *(const short8*)(Kp + (size_t)(kt + rB) * 3072 + oB);
    *(short8*)(&Vs[rA][oA]) = *(const short8*)(Vtp + (size_t)rA * Nseq + kt + oA);
    *(short8*)(&Vs[rB][oB]) = *(const short8*)(Vtp + (size_t)rB * Nseq + kt + oB);
    __syncthreads();

    // S^T = K Q^T : lane holds keys (st*16 + l4*4 + e) for q = q0 + l15
    f32x4 S[4];
#pragma unroll
    for (int st = 0; st < 4; ++st) {
      f32x4 acc = {};
      acc = MFMA16(*(const short8*)(&Ks[st * 16 + l15][l4 * 8]), qf[0], acc);
      acc = MFMA16(*(const short8*)(&Ks[st * 16 + l15][32 + l4 * 8]), qf[1], acc);
      S[st] = acc;
    }

    // online softmax over this lane's 16 keys + across l4 groups
    float pm = S[0][0];
#pragma unroll
    for (int st = 0; st < 4; ++st)
#pragma unroll
      for (int e = 0; e < 4; ++e) pm = fmaxf(pm, S[st][e]);
    pm = fmaxf(pm, __shfl_xor(pm, 16));
    pm = fmaxf(pm, __shfl_xor(pm, 32));
    pm *= 0.125f;

    const float mn = fmaxf(m, pm);
    const float fac = __expf(m - mn);
    m = mn;

    float rs = 0.f;
#pragma unroll
    for (int st = 0; st < 4; ++st) {
      float p0 = __expf(S[st][0] * 0.125f - mn);
      float p1 = __expf(S[st][1] * 0.125f - mn);
      float p2 = __expf(S[st][2] * 0.125f - mn);
      float p3 = __expf(S[st][3] * 0.125f - mn);
      rs += (p0 + p1) + (p2 + p3);
      unsigned u0 = (unsigned)f2bf(p0) | ((unsigned)f2bf(p1) << 16);
      unsigned u1 = (unsigned)f2bf(p2) | ((unsigned)f2bf(p3) << 16);
      *(unsigned*)(&Pl[w][l15][st * 16 + l4 * 4]) = u0;
      *(unsigned*)(&Pl[w][l15][st * 16 + l4 * 4 + 2]) = u1;
    }
    rs += __shfl_xor(rs, 16);
    rs += __shfl_xor(rs, 32);
    ls = ls * fac + rs;

    float fj[4];
#pragma unroll
    for (int j = 0; j < 4; ++j) fj[j] = __shfl(fac, l4 * 4 + j);
#pragma unroll
    for (int fd = 0; fd < 4; ++fd)
#pragma unroll
      for (int j = 0; j < 4; ++j) O[fd][j] *= fj[j];

    // O += P @ V   (A = P rows q, B = Vt rows d)
#pragma unroll
    for (int kb = 0; kb < 2; ++kb) {
      short8 pf = *(const short8*)(&Pl[w][l15][kb * 32 + l4 * 8]);
#pragma unroll
      for (int fd = 0; fd < 4; ++fd)
        O[fd] = MFMA16(pf, *(const short8*)(&Vs[fd * 16 + l15][kb * 32 + l4 * 8]), O[fd]);
    }
    __syncthreads();
  }

  float* Op = s ? Op1 : Op0;
#pragma unroll
  for (int fd = 0; fd < 4; ++fd)
#pragma unroll
    for (int j = 0; j < 4; ++j)
      Op[(size_t)(q0 + l4 * 4 + j) * 1024 + head * 64 + fd * 16 + l15] = O[fd][j];
  if (lane < 16) {
    Ml[(size_t)(s * 16 + head) * Nseq + q0 + lane] = m;
    Ll[(size_t)(s * 16 + head) * Nseq + q0 + lane] = ls;
  }
}

// ---------------------------------------------------------------------------
// Combine the two key-split partials -> bf16 attention output
// ---------------------------------------------------------------------------
__global__ __launch_bounds__(256) void attn_combine(const float* __restrict__ Op0,
                                                    const float* __restrict__ Op1,
                                                    const float* __restrict__ Ml,
                                                    const float* __restrict__ Ll,
                                                    unsigned short* __restrict__ out, int Nseq) {
  const int t = blockIdx.x * 256 + threadIdx.x;
  const int q = t >> 8, c4 = (t & 255) * 4;
  const int head = c4 >> 6;
  const float m1 = Ml[head * Nseq + q], m2 = Ml[(16 + head) * Nseq + q];
  const float l1 = Ll[head * Nseq + q], l2 = Ll[(16 + head) * Nseq + q];
  const float M = fmaxf(m1, m2);
  const float w1 = __expf(m1 - M), w2 = __expf(m2 - M);
  const float inv = 1.f / (l1 * w1 + l2 * w2);
  float4v o1 = *(const float4v*)(Op0 + (size_t)q * 1024 + c4);
  float4v o2 = *(const float4v*)(Op1 + (size_t)q * 1024 + c4);
  ushort4v r;
  r.x = f2bf((o1.x * w1 + o2.x * w2) * inv);
  r.y = f2bf((o1.y * w1 + o2.y * w2) * inv);
  r.z = f2bf((o1.z * w1 + o2.z * w2) * inv);
  r.w = f2bf((o1.w * w1 + o2.w * w2) * inv);
  *(ushort4v*)(out + (size_t)q * 1024 + c4) = r;
}

// ---------------------------------------------------------------------------
// Row LayerNorm (two-pass, fp32).  One block (256 thr) per row.
// ---------------------------------------------------------------------------
template <int D>
__global__ __launch_bounds__(256) void ln_rows(const float* __restrict__ src,
                                               const float* __restrict__ gw,
                                               const float* __restrict__ bw,
                                               float* __restrict__ outF,
                                               unsigned short* __restrict__ outB) {
  __shared__ float red[4];
  const int row = blockIdx.x;
  const int tid = threadIdx.x, w = tid >> 6;
  constexpr int PT = D / 256;
  const float* r = src + (size_t)row * D;
  float v[PT];
  float s = 0.f;
#pragma unroll
  for (int i = 0; i < PT; ++i) { v[i] = r[tid + i * 256]; s += v[i]; }
#pragma unroll
  for (int off = 32; off; off >>= 1) s += __shfl_down(s, off);
  if ((tid & 63) == 0) red[w] = s;
  __syncthreads();
  const float mean = (red[0] + red[1] + red[2] + red[3]) / D;
  __syncthreads();
  float q = 0.f;
#pragma unroll
  for (int i = 0; i < PT; ++i) { const float d = v[i] - mean; q += d * d; }
#pragma unroll
  for (int off = 32; off; off >>= 1) q += __shfl_down(q, off);
  if ((tid & 63) == 0) red[w] = q;
  __syncthreads();
  const float rstd = rsqrtf((red[0] + red[1] + red[2] + red[3]) / D + 1e-5f);
#pragma unroll
  for (int i = 0; i < PT; ++i) {
    const int c = tid + i * 256;
    const float o = (v[i] - mean) * rstd * gw[c] + bw[c];
    outF[(size_t)row * D + c] = o;
    if (outB) outB[(size_t)row * D + c] = f2bf(o);
  }
}

// ---------------------------------------------------------------------------
// Orchestration
// ---------------------------------------------------------------------------
extern "C" void kernel_launch(void* const* d_in, const int* in_sizes, int n_in,
                              void* d_out, int out_size, void* d_ws, size_t ws_size,
                              hipStream_t stream) {
  const int N = 2048, D_IN = 512, H = 1024, D_OUT = 256, NL = 4;
  const float* x    = (const float*)d_in[0];
  const float* W1   = (const float*)d_in[1];
  const float* b1   = (const float*)d_in[2];
  const float* Wqkv = (const float*)d_in[3];
  const float* bqkv = (const float*)d_in[4];
  const float* Wo   = (const float*)d_in[5];
  const float* bo   = (const float*)d_in[6];
  const float* lng  = (const float*)d_in[7];
  const float* lnb  = (const float*)d_in[8];
  const float* W2   = (const float*)d_in[9];
  const float* b2   = (const float*)d_in[10];
  const float* gout = (const float*)d_in[11];
  const float* bout = (const float*)d_in[12];
  float* out = (float*)d_out;

  char* ws = (char*)d_ws;
  auto alloc = [&](size_t bytes) -> char* {
    char* p = ws;
    ws += (bytes + 255) & ~(size_t)255;
    return p;
  };
  unsigned short* xb    = (unsigned short*)alloc((size_t)N * D_IN * 2);
  unsigned short* W1b   = (unsigned short*)alloc((size_t)H * D_IN * 2);
  unsigned short* Wqkvb = (unsigned short*)alloc((size_t)NL * 3 * H * H * 2);
  unsigned short* Wob   = (unsigned short*)alloc((size_t)NL * H * H * 2);
  unsigned short* W2b   = (unsigned short*)alloc((size_t)D_OUT * H * 2);
  unsigned short* hb    = (unsigned short*)alloc((size_t)N * H * 2);
  unsigned short* qkvb  = (unsigned short*)alloc((size_t)N * 3 * H * 2);
  unsigned short* aob   = (unsigned short*)alloc((size_t)N * H * 2);
  unsigned short* vtg   = (unsigned short*)alloc((size_t)H * N * 2);
  float* hf  = (float*)alloc((size_t)N * H * 4);
  float* af  = (float*)alloc((size_t)N * H * 4);   // also aliased as attn partial Op0
  float* op1 = (float*)alloc((size_t)N * H * 4);
  float* ml  = (float*)alloc((size_t)2 * 16 * N * 4);
  float* ll  = (float*)alloc((size_t)2 * 16 * N * 4);
  float* yf  = (float*)alloc((size_t)N * D_OUT * 4);
  float* op0 = af;  // safe: combine consumes op0 before o-proj writes af

  auto cvt = [&](const float* s, unsigned short* d, int n) {
    int blocks = (n / 4 + 255) / 256;
    if (blocks > 2048) blocks = 2048;
    cvt_bf16<<<blocks, 256, 0, stream>>>(s, d, n);
  };
  cvt(x, xb, N * D_IN);
  cvt(W1, W1b, H * D_IN);
  cvt(Wqkv, Wqkvb, NL * 3 * H * H);
  cvt(Wo, Wob, NL * H * H);
  cvt(W2, W2b, D_OUT * H);

  // FC1: h = relu(x @ W1^T + b1) -> hf, hb
  gemm_bt<true, false, true, true><<<dim3(H / 128, N / 128), 256, 0, stream>>>(
      xb, W1b, b1, nullptr, hf, hb, N, H, D_IN);

  for (int l = 0; l < NL; ++l) {
    gemm_bt<false, false, false, true><<<dim3(3 * H / 128, N / 128), 256, 0, stream>>>(
        hb, Wqkvb + (size_t)l * 3 * H * H, bqkv + (size_t)l * 3 * H, nullptr, nullptr, qkvb,
        N, 3 * H, H);
    transpose_v<<<dim3(N / 64, H / 64), 256, 0, stream>>>(qkvb, vtg, N);
    flash_attn2<<<1024, 256, 0, stream>>>(qkvb, vtg, op0, op1, ml, ll, N);
    attn_combine<<<(N * H / 4) / 256, 256, 0, stream>>>(op0, op1, ml, ll, aob, N);
    gemm_bt<false, true, true, false><<<dim3(H / 128, N / 128), 256, 0, stream>>>(
        aob, Wob + (size_t)l * H * H, bo + (size_t)l * H, hf, af, nullptr, N, H, H);
    ln_rows<1024><<<N, 256, 0, stream>>>(af, lng + (size_t)l * H, lnb + (size_t)l * H, hf, hb);
  }

  gemm_bt<true, false, true, false><<<dim3(D_OUT / 128, N / 128), 256, 0, stream>>>(
      hb, W2b, b2, nullptr, yf, nullptr, N, D_OUT, H);
  ln_rows<256><<<N, 256, 0, stream>>>(yf, gout, bout, out, nullptr);
}

// Round 3
// 495.501 us; speedup vs baseline: 1.5364x; 1.0858x over previous
//
#include <hip/hip_runtime.h>

// ---------------------------------------------------------------------------
// Types / helpers
// ---------------------------------------------------------------------------
typedef __attribute__((ext_vector_type(8))) short short8;     // 8 bf16 (4 VGPR)
typedef __attribute__((ext_vector_type(4))) float f32x4;      // mfma C/D frag
typedef __attribute__((ext_vector_type(4))) float float4v;
typedef __attribute__((ext_vector_type(4))) unsigned short ushort4v;
typedef __attribute__((ext_vector_type(2))) unsigned int uint2v;

#define MFMA16(a, b, c) __builtin_amdgcn_mfma_f32_16x16x32_bf16((a), (b), (c), 0, 0, 0)
#define GLOAD_LDS16(g, s)                                                         \
  __builtin_amdgcn_global_load_lds((const __attribute__((address_space(1))) void*)(g), \
                                   (__attribute__((address_space(3))) void*)(s), 16, 0, 0)
#define EXP2(x) __builtin_amdgcn_exp2f(x)

__device__ __forceinline__ unsigned short f2bf(float f) {
  unsigned u = __builtin_bit_cast(unsigned, f);
  u += 0x7fffu + ((u >> 16) & 1u);   // round-to-nearest-even
  return (unsigned short)(u >> 16);
}

// ---------------------------------------------------------------------------
// fp32 -> bf16 convert (vectorized, grid-stride)
// ---------------------------------------------------------------------------
__global__ __launch_bounds__(256) void cvt_bf16(const float* __restrict__ src,
                                                unsigned short* __restrict__ dst, int n) {
  int i = (blockIdx.x * 256 + threadIdx.x) * 4;
  int stride = gridDim.x * 256 * 4;
  for (; i < n; i += stride) {
    float4v v = *(const float4v*)(src + i);
    ushort4v o;
    o.x = f2bf(v.x); o.y = f2bf(v.y); o.z = f2bf(v.z); o.w = f2bf(v.w);
    *(ushort4v*)(dst + i) = o;
  }
}

// ---------------------------------------------------------------------------
// GEMM: C[M][N] = act(A[M][K] @ B[N][K]^T + bias[N]) (+ residual)
// ---------------------------------------------------------------------------
template <bool RELU, bool RES, bool OUTF, bool OUTB>
__global__ __launch_bounds__(256) void gemm_bt(const unsigned short* __restrict__ A,
                                               const unsigned short* __restrict__ B,
                                               const float* __restrict__ bias,
                                               const float* __restrict__ res,
                                               float* __restrict__ outF,
                                               unsigned short* __restrict__ outB,
                                               int M, int N, int K) {
  __shared__ __align__(16) unsigned short As[128 * 32];
  __shared__ __align__(16) unsigned short Bs[128 * 32];
  const int tid = threadIdx.x;
  const int w = tid >> 6, lane = tid & 63;
  const int l15 = lane & 15, l4 = lane >> 4;
  const int rowBase = blockIdx.y * 128, colBase = blockIdx.x * 128;
  const int wm = w >> 1, wn = w & 1;

  f32x4 acc[4][4] = {};

  const int c0 = w * 64 + lane;
  const int c1 = 256 + c0;

  for (int k0 = 0; k0 < K; k0 += 32) {
    const unsigned short* ga0 = A + (size_t)(rowBase + (c0 >> 2)) * K + k0 + ((c0 & 3) << 3);
    const unsigned short* ga1 = A + (size_t)(rowBase + (c1 >> 2)) * K + k0 + ((c1 & 3) << 3);
    GLOAD_LDS16(ga0, As + w * 512);
    GLOAD_LDS16(ga1, As + 2048 + w * 512);
    const unsigned short* gb0 = B + (size_t)(colBase + (c0 >> 2)) * K + k0 + ((c0 & 3) << 3);
    const unsigned short* gb1 = B + (size_t)(colBase + (c1 >> 2)) * K + k0 + ((c1 & 3) << 3);
    GLOAD_LDS16(gb0, Bs + w * 512);
    GLOAD_LDS16(gb1, Bs + 2048 + w * 512);
    __syncthreads();

    short8 af[4], bf[4];
#pragma unroll
    for (int f = 0; f < 4; ++f) {
      af[f] = *(const short8*)(As + (wm * 64 + f * 16 + l15) * 32 + l4 * 8);
      bf[f] = *(const short8*)(Bs + (wn * 64 + f * 16 + l15) * 32 + l4 * 8);
    }
#pragma unroll
    for (int i = 0; i < 4; ++i)
#pragma unroll
      for (int j = 0; j < 4; ++j)
        acc[i][j] = MFMA16(af[i], bf[j], acc[i][j]);
    __syncthreads();
  }

#pragma unroll
  for (int i = 0; i < 4; ++i) {
    const int row0 = rowBase + wm * 64 + i * 16 + l4 * 4;
#pragma unroll
    for (int j = 0; j < 4; ++j) {
      const int col = colBase + wn * 64 + j * 16 + l15;
      const float bv = bias[col];
#pragma unroll
      for (int e = 0; e < 4; ++e) {
        const int row = row0 + e;
        float v = acc[i][j][e] + bv;
        if constexpr (RELU) v = fmaxf(v, 0.f);
        if constexpr (RES) v += res[(size_t)row * N + col];
        if constexpr (OUTF) outF[(size_t)row * N + col] = v;
        if constexpr (OUTB) outB[(size_t)row * N + col] = f2bf(v);
      }
    }
  }
}

// ---------------------------------------------------------------------------
// V transpose: vt[c][r] = qkv[r][2048+c], c in [0,1024), r in [0,N)
// ---------------------------------------------------------------------------
__global__ __launch_bounds__(256) void transpose_v(const unsigned short* __restrict__ qkv,
                                                   unsigned short* __restrict__ vt, int Nseq) {
  __shared__ unsigned short T[64][72];
  const int r0 = blockIdx.x * 64;   // k rows
  const int c0 = blockIdx.y * 64;   // v cols
  const int tid = threadIdx.x;
#pragma unroll
  for (int i = 0; i < 2; ++i) {
    int c = tid * 2 + i;
    int r = c >> 3, off = (c & 7) * 8;
    short8 v = *(const short8*)(qkv + (size_t)(r0 + r) * 3072 + 2048 + c0 + off);
    *(short8*)(&T[r][off]) = v;
  }
  __syncthreads();
#pragma unroll
  for (int i = 0; i < 2; ++i) {
    int c = tid * 2 + i;
    int orow = c >> 3, off = (c & 7) * 8;
    short8 v;
#pragma unroll
    for (int e = 0; e < 8; ++e) v[e] = T[off + e][orow];
    *(short8*)(vt + (size_t)(c0 + orow) * Nseq + r0 + off) = v;
  }
}

// ---------------------------------------------------------------------------
// Flash attention v3.
// Swapped QK^T (S^T = mfma(K, Q)); 4 waves x 32 q-rows = 128 q/block; KVBLK=64;
// split-K=2 over keys; XOR-swizzled LDS (16B unit ^= row&7) for K and Vt;
// double-buffered K/V staging (issue-early / write-late); exp2-domain softmax
// with defer-max rescale (threshold 8).
// ---------------------------------------------------------------------------
__global__ __launch_bounds__(256, 2) void flash_attn3(const unsigned short* __restrict__ qkv,
                                                      const unsigned short* __restrict__ vt,
                                                      float* __restrict__ Op0,
                                                      float* __restrict__ Op1,
                                                      float* __restrict__ Ml,
                                                      float* __restrict__ Ll,
                                                      int Nseq) {
  __shared__ __align__(16) unsigned short Ks[2][64 * 64];
  __shared__ __align__(16) unsigned short Vs[2][64 * 64];
  __shared__ __align__(16) unsigned short Pl[4][32 * 64];
  const int tid = threadIdx.x, w = tid >> 6, lane = tid & 63;
  const int l15 = lane & 15, l4 = lane >> 4, l7 = l15 & 7;
  const float CSC = 0.18033688011112042f;   // 0.125 * log2(e)

  // 512 blocks: head tied to XCD slot for K/V L2 locality
  const int b = blockIdx.x;
  const int head = (b & 7) * 2 + ((b >> 3) & 1);
  const int rem = b >> 4;                 // 0..31
  const int s = rem & 1;
  const int q0 = (rem >> 1) * 128 + w * 32;

  const unsigned short* Qp = qkv + head * 64;
  const unsigned short* Kp = qkv + 1024 + head * 64;
  const unsigned short* Vtp = vt + (size_t)head * 64 * Nseq;

  short8 qf[2][2];
#pragma unroll
  for (int qi = 0; qi < 2; ++qi)
#pragma unroll
    for (int kb = 0; kb < 2; ++kb)
      qf[qi][kb] = *(const short8*)(Qp + (size_t)(q0 + qi * 16 + l15) * 3072 + kb * 32 + l4 * 8);

  // staging geometry: thread covers 2 chunks (row, 16B-unit)
  const int srow0 = tid >> 3, su = tid & 7;
  const int srow1 = srow0 + 32;
  const int sOff0 = srow0 * 64 + ((su ^ (srow0 & 7)) * 8);
  const int sOff1 = srow1 * 64 + ((su ^ (srow1 & 7)) * 8);

  float mt[2] = {-1e30f, -1e30f};
  float ls[2] = {0.f, 0.f};
  f32x4 O[2][4] = {};
  unsigned short* PlW = Pl[w];

  const int kt0 = s * (Nseq >> 1);
  const int NIT = (Nseq >> 1) >> 6;

  // prologue: stage tile 0
  short8 k0 = *(const short8*)(Kp + (size_t)(kt0 + srow0) * 3072 + su * 8);
  short8 k1 = *(const short8*)(Kp + (size_t)(kt0 + srow1) * 3072 + su * 8);
  short8 v0 = *(const short8*)(Vtp + (size_t)srow0 * Nseq + kt0 + su * 8);
  short8 v1 = *(const short8*)(Vtp + (size_t)srow1 * Nseq + kt0 + su * 8);
  *(short8*)(Ks[0] + sOff0) = k0;
  *(short8*)(Ks[0] + sOff1) = k1;
  *(short8*)(Vs[0] + sOff0) = v0;
  *(short8*)(Vs[0] + sOff1) = v1;
  __syncthreads();

  int p = 0;
  for (int it = 0; it < NIT; ++it) {
    const int ktn = kt0 + (it + 1) * 64;
    const bool more = it + 1 < NIT;
    if (more) {   // issue next-tile loads early; written to LDS after compute
      k0 = *(const short8*)(Kp + (size_t)(ktn + srow0) * 3072 + su * 8);
      k1 = *(const short8*)(Kp + (size_t)(ktn + srow1) * 3072 + su * 8);
      v0 = *(const short8*)(Vtp + (size_t)srow0 * Nseq + ktn + su * 8);
      v1 = *(const short8*)(Vtp + (size_t)srow1 * Nseq + ktn + su * 8);
    }
    const unsigned short* KS = Ks[p];
    const unsigned short* VS = Vs[p];

    // S^T tiles: lane holds S[key = st*16 + l4*4 + e][q = q0 + qi*16 + l15]
    f32x4 S[2][4];
#pragma unroll
    for (int st = 0; st < 4; ++st) {
      const int rb = (st * 16 + l15) * 64;
      const short8 kf0 = *(const short8*)(KS + rb + ((l4 ^ l7) * 8));
      const short8 kf1 = *(const short8*)(KS + rb + (((4 | l4) ^ l7) * 8));
#pragma unroll
      for (int qi = 0; qi < 2; ++qi) {
        f32x4 a = {};
        a = MFMA16(kf0, qf[qi][0], a);
        a = MFMA16(kf1, qf[qi][1], a);
        S[qi][st] = a;
      }
    }

    // tile max (raw S domain), reduce across l4 groups
    float pm[2];
#pragma unroll
    for (int qi = 0; qi < 2; ++qi) {
      float m0 = S[qi][0][0];
#pragma unroll
      for (int st = 0; st < 4; ++st)
#pragma unroll
        for (int e = 0; e < 4; ++e) m0 = fmaxf(m0, S[qi][st][e]);
      m0 = fmaxf(m0, __shfl_xor(m0, 16));
      m0 = fmaxf(m0, __shfl_xor(m0, 32));
      pm[qi] = m0 * CSC;
    }

    // defer-max: only rescale when some row grew past threshold
    if (__any((pm[0] > mt[0] + 8.f) || (pm[1] > mt[1] + 8.f))) {
      float fac[2];
#pragma unroll
      for (int qi = 0; qi < 2; ++qi) {
        const float mn = fmaxf(mt[qi], pm[qi]);
        fac[qi] = EXP2(mt[qi] - mn);
        mt[qi] = mn;
        ls[qi] *= fac[qi];
      }
#pragma unroll
      for (int j = 0; j < 4; ++j) {
        const float g0 = __shfl(fac[0], l4 * 4 + j);
        const float g1 = __shfl(fac[1], l4 * 4 + j);
#pragma unroll
        for (int fd = 0; fd < 4; ++fd) {
          O[0][fd][j] *= g0;
          O[1][fd][j] *= g1;
        }
      }
    }

    // P = exp2(S*CSC - mt), pack to bf16 into swizzled per-wave LDS
    float rs[2] = {0.f, 0.f};
#pragma unroll
    for (int qi = 0; qi < 2; ++qi) {
#pragma unroll
      for (int st = 0; st < 4; ++st) {
        const float p0 = EXP2(fmaf(S[qi][st][0], CSC, -mt[qi]));
        const float p1 = EXP2(fmaf(S[qi][st][1], CSC, -mt[qi]));
        const float p2 = EXP2(fmaf(S[qi][st][2], CSC, -mt[qi]));
        const float p3 = EXP2(fmaf(S[qi][st][3], CSC, -mt[qi]));
        rs[qi] += (p0 + p1) + (p2 + p3);
        uint2v uu;
        uu.x = (unsigned)f2bf(p0) | ((unsigned)f2bf(p1) << 16);
        uu.y = (unsigned)f2bf(p2) | ((unsigned)f2bf(p3) << 16);
        *(uint2v*)(PlW + (qi * 16 + l15) * 64 +
                   (((st * 2 + (l4 >> 1)) ^ l7) * 8 + (l4 & 1) * 4)) = uu;
      }
    }
#pragma unroll
    for (int qi = 0; qi < 2; ++qi) {
      rs[qi] += __shfl_xor(rs[qi], 16);
      rs[qi] += __shfl_xor(rs[qi], 32);
      ls[qi] += rs[qi];
    }

    // O += P @ V
    short8 pf[2][2];
#pragma unroll
    for (int qi = 0; qi < 2; ++qi) {
      pf[qi][0] = *(const short8*)(PlW + (qi * 16 + l15) * 64 + ((l4 ^ l7) * 8));
      pf[qi][1] = *(const short8*)(PlW + (qi * 16 + l15) * 64 + (((4 | l4) ^ l7) * 8));
    }
#pragma unroll
    for (int fd = 0; fd < 4; ++fd) {
      const int rb = (fd * 16 + l15) * 64;
      const short8 vf0 = *(const short8*)(VS + rb + ((l4 ^ l7) * 8));
      const short8 vf1 = *(const short8*)(VS + rb + (((4 | l4) ^ l7) * 8));
#pragma unroll
      for (int qi = 0; qi < 2; ++qi) {
        O[qi][fd] = MFMA16(pf[qi][0], vf0, O[qi][fd]);
        O[qi][fd] = MFMA16(pf[qi][1], vf1, O[qi][fd]);
      }
    }

    if (more) {   // write next tile into the other buffer
      unsigned short* Kn = Ks[p ^ 1];
      unsigned short* Vn = Vs[p ^ 1];
      *(short8*)(Kn + sOff0) = k0;
      *(short8*)(Kn + sOff1) = k1;
      *(short8*)(Vn + sOff0) = v0;
      *(short8*)(Vn + sOff1) = v1;
    }
    __syncthreads();
    p ^= 1;
  }

  float* Op = s ? Op1 : Op0;
#pragma unroll
  for (int qi = 0; qi < 2; ++qi) {
#pragma unroll
    for (int fd = 0; fd < 4; ++fd)
#pragma unroll
      for (int j = 0; j < 4; ++j)
        Op[(size_t)(q0 + qi * 16 + l4 * 4 + j) * 1024 + head * 64 + fd * 16 + l15] = O[qi][fd][j];
    if (l4 == 0) {
      Ml[(size_t)(s * 16 + head) * Nseq + q0 + qi * 16 + l15] = mt[qi];
      Ll[(size_t)(s * 16 + head) * Nseq + q0 + qi * 16 + l15] = ls[qi];
    }
  }
}

// ---------------------------------------------------------------------------
// Combine the two key-split partials (exp2 domain) -> bf16 attention output
// ---------------------------------------------------------------------------
__global__ __launch_bounds__(256) void attn_combine(const float* __restrict__ Op0,
                                                    const float* __restrict__ Op1,
                                                    const float* __restrict__ Ml,
                                                    const float* __restrict__ Ll,
                                                    unsigned short* __restrict__ out, int Nseq) {
  const int t = blockIdx.x * 256 + threadIdx.x;
  const int q = t >> 8, c4 = (t & 255) * 4;
  const int head = c4 >> 6;
  const float m1 = Ml[head * Nseq + q], m2 = Ml[(16 + head) * Nseq + q];
  const float l1 = Ll[head * Nseq + q], l2 = Ll[(16 + head) * Nseq + q];
  const float M = fmaxf(m1, m2);
  const float w1 = EXP2(m1 - M), w2 = EXP2(m2 - M);
  const float inv = 1.f / (l1 * w1 + l2 * w2);
  float4v o1 = *(const float4v*)(Op0 + (size_t)q * 1024 + c4);
  float4v o2 = *(const float4v*)(Op1 + (size_t)q * 1024 + c4);
  ushort4v r;
  r.x = f2bf((o1.x * w1 + o2.x * w2) * inv);
  r.y = f2bf((o1.y * w1 + o2.y * w2) * inv);
  r.z = f2bf((o1.z * w1 + o2.z * w2) * inv);
  r.w = f2bf((o1.w * w1 + o2.w * w2) * inv);
  *(ushort4v*)(out + (size_t)q * 1024 + c4) = r;
}

// ---------------------------------------------------------------------------
// Row LayerNorm (two-pass, fp32).  One block (256 thr) per row.
// ---------------------------------------------------------------------------
template <int D>
__global__ __launch_bounds__(256) void ln_rows(const float* __restrict__ src,
                                               const float* __restrict__ gw,
                                               const float* __restrict__ bw,
                                               float* __restrict__ outF,
                                               unsigned short* __restrict__ outB) {
  __shared__ float red[4];
  const int row = blockIdx.x;
  const int tid = threadIdx.x, w = tid >> 6;
  constexpr int PT = D / 256;
  const float* r = src + (size_t)row * D;
  float v[PT];
  float s = 0.f;
#pragma unroll
  for (int i = 0; i < PT; ++i) { v[i] = r[tid + i * 256]; s += v[i]; }
#pragma unroll
  for (int off = 32; off; off >>= 1) s += __shfl_down(s, off);
  if ((tid & 63) == 0) red[w] = s;
  __syncthreads();
  const float mean = (red[0] + red[1] + red[2] + red[3]) / D;
  __syncthreads();
  float q = 0.f;
#pragma unroll
  for (int i = 0; i < PT; ++i) { const float d = v[i] - mean; q += d * d; }
#pragma unroll
  for (int off = 32; off; off >>= 1) q += __shfl_down(q, off);
  if ((tid & 63) == 0) red[w] = q;
  __syncthreads();
  const float rstd = rsqrtf((red[0] + red[1] + red[2] + red[3]) / D + 1e-5f);
#pragma unroll
  for (int i = 0; i < PT; ++i) {
    const int c = tid + i * 256;
    const float o = (v[i] - mean) * rstd * gw[c] + bw[c];
    outF[(size_t)row * D + c] = o;
    if (outB) outB[(size_t)row * D + c] = f2bf(o);
  }
}

// ---------------------------------------------------------------------------
// Orchestration
// ---------------------------------------------------------------------------
extern "C" void kernel_launch(void* const* d_in, const int* in_sizes, int n_in,
                              void* d_out, int out_size, void* d_ws, size_t ws_size,
                              hipStream_t stream) {
  const int N = 2048, D_IN = 512, H = 1024, D_OUT = 256, NL = 4;
  const float* x    = (const float*)d_in[0];
  const float* W1   = (const float*)d_in[1];
  const float* b1   = (const float*)d_in[2];
  const float* Wqkv = (const float*)d_in[3];
  const float* bqkv = (const float*)d_in[4];
  const float* Wo   = (const float*)d_in[5];
  const float* bo   = (const float*)d_in[6];
  const float* lng  = (const float*)d_in[7];
  const float* lnb  = (const float*)d_in[8];
  const float* W2   = (const float*)d_in[9];
  const float* b2   = (const float*)d_in[10];
  const float* gout = (const float*)d_in[11];
  const float* bout = (const float*)d_in[12];
  float* out = (float*)d_out;

  char* ws = (char*)d_ws;
  auto alloc = [&](size_t bytes) -> char* {
    char* p = ws;
    ws += (bytes + 255) & ~(size_t)255;
    return p;
  };
  unsigned short* xb    = (unsigned short*)alloc((size_t)N * D_IN * 2);
  unsigned short* W1b   = (unsigned short*)alloc((size_t)H * D_IN * 2);
  unsigned short* Wqkvb = (unsigned short*)alloc((size_t)NL * 3 * H * H * 2);
  unsigned short* Wob   = (unsigned short*)alloc((size_t)NL * H * H * 2);
  unsigned short* W2b   = (unsigned short*)alloc((size_t)D_OUT * H * 2);
  unsigned short* hb    = (unsigned short*)alloc((size_t)N * H * 2);
  unsigned short* qkvb  = (unsigned short*)alloc((size_t)N * 3 * H * 2);
  unsigned short* aob   = (unsigned short*)alloc((size_t)N * H * 2);
  unsigned short* vtg   = (unsigned short*)alloc((size_t)H * N * 2);
  float* hf  = (float*)alloc((size_t)N * H * 4);
  float* af  = (float*)alloc((size_t)N * H * 4);   // also aliased as attn partial Op0
  float* op1 = (float*)alloc((size_t)N * H * 4);
  float* ml  = (float*)alloc((size_t)2 * 16 * N * 4);
  float* ll  = (float*)alloc((size_t)2 * 16 * N * 4);
  float* yf  = (float*)alloc((size_t)N * D_OUT * 4);
  float* op0 = af;  // safe: combine consumes op0 before o-proj writes af

  auto cvt = [&](const float* s, unsigned short* d, int n) {
    int blocks = (n / 4 + 255) / 256;
    if (blocks > 2048) blocks = 2048;
    cvt_bf16<<<blocks, 256, 0, stream>>>(s, d, n);
  };
  cvt(x, xb, N * D_IN);
  cvt(W1, W1b, H * D_IN);
  cvt(Wqkv, Wqkvb, NL * 3 * H * H);
  cvt(Wo, Wob, NL * H * H);
  cvt(W2, W2b, D_OUT * H);

  // FC1: h = relu(x @ W1^T + b1) -> hf, hb
  gemm_bt<true, false, true, true><<<dim3(H / 128, N / 128), 256, 0, stream>>>(
      xb, W1b, b1, nullptr, hf, hb, N, H, D_IN);

  for (int l = 0; l < NL; ++l) {
    gemm_bt<false, false, false, true><<<dim3(3 * H / 128, N / 128), 256, 0, stream>>>(
        hb, Wqkvb + (size_t)l * 3 * H * H, bqkv + (size_t)l * 3 * H, nullptr, nullptr, qkvb,
        N, 3 * H, H);
    transpose_v<<<dim3(N / 64, H / 64), 256, 0, stream>>>(qkvb, vtg, N);
    flash_attn3<<<512, 256, 0, stream>>>(qkvb, vtg, op0, op1, ml, ll, N);
    attn_combine<<<(N * H / 4) / 256, 256, 0, stream>>>(op0, op1, ml, ll, aob, N);
    gemm_bt<false, true, true, false><<<dim3(H / 128, N / 128), 256, 0, stream>>>(
        aob, Wob + (size_t)l * H * H, bo + (size_t)l * H, hf, af, nullptr, N, H, H);
    ln_rows<1024><<<N, 256, 0, stream>>>(af, lng + (size_t)l * H, lnb + (size_t)l * H, hf, hb);
  }

  gemm_bt<true, false, true, false><<<dim3(D_OUT / 128, N / 128), 256, 0, stream>>>(
      hb, W2b, b2, nullptr, yf, nullptr, N, D_OUT, H);
  ln_rows<256><<<N, 256, 0, stream>>>(yf, gout, bout, out, nullptr);
}

// Round 4
// 484.498 us; speedup vs baseline: 1.5713x; 1.0227x over previous
//
#include <hip/hip_runtime.h>

// ---------------------------------------------------------------------------
// Types / helpers
// ---------------------------------------------------------------------------
typedef __attribute__((ext_vector_type(8))) short short8;      // 8 bf16
typedef __attribute__((ext_vector_type(4))) float f32x4;
typedef __attribute__((ext_vector_type(16))) float f32x16;     // 32x32 mfma acc
typedef __attribute__((ext_vector_type(4))) float float4v;
typedef __attribute__((ext_vector_type(4))) unsigned short ushort4v;
typedef __attribute__((ext_vector_type(4))) unsigned int uint4v;

#define MFMA16(a, b, c) __builtin_amdgcn_mfma_f32_16x16x32_bf16((a), (b), (c), 0, 0, 0)
#define MFMA32(a, b, c) __builtin_amdgcn_mfma_f32_32x32x16_bf16((a), (b), (c), 0, 0, 0)
#define GLOAD_LDS16(g, s)                                                         \
  __builtin_amdgcn_global_load_lds((const __attribute__((address_space(1))) void*)(g), \
                                   (__attribute__((address_space(3))) void*)(s), 16, 0, 0)
#define EXP2(x) __builtin_amdgcn_exp2f(x)

__device__ __forceinline__ unsigned short f2bf(float f) {
  unsigned u = __builtin_bit_cast(unsigned, f);
  u += 0x7fffu + ((u >> 16) & 1u);   // round-to-nearest-even
  return (unsigned short)(u >> 16);
}

__device__ __forceinline__ unsigned cvtpk(float lo, float hi) {
  unsigned r;
  asm("v_cvt_pk_bf16_f32 %0, %1, %2" : "=v"(r) : "v"(lo), "v"(hi));
  return r;
}

// v_permlane32_swap_b32 a, b: a[32:63] <-> b[0:31]
__device__ __forceinline__ void swap32(unsigned& a, unsigned& b) {
  asm volatile("v_permlane32_swap_b32 %0, %1" : "+v"(a), "+v"(b));
}

// ---------------------------------------------------------------------------
// fp32 -> bf16 convert (vectorized, grid-stride)
// ---------------------------------------------------------------------------
__global__ __launch_bounds__(256) void cvt_bf16(const float* __restrict__ src,
                                                unsigned short* __restrict__ dst, int n) {
  int i = (blockIdx.x * 256 + threadIdx.x) * 4;
  int stride = gridDim.x * 256 * 4;
  for (; i < n; i += stride) {
    float4v v = *(const float4v*)(src + i);
    ushort4v o;
    o.x = f2bf(v.x); o.y = f2bf(v.y); o.z = f2bf(v.z); o.w = f2bf(v.w);
    *(ushort4v*)(dst + i) = o;
  }
}

// ---------------------------------------------------------------------------
// GEMM: C[M][N] = act(A[M][K] @ B[N][K]^T + bias[N]) (+ residual)
// ---------------------------------------------------------------------------
template <bool RELU, bool RES, bool OUTF, bool OUTB>
__global__ __launch_bounds__(256) void gemm_bt(const unsigned short* __restrict__ A,
                                               const unsigned short* __restrict__ B,
                                               const float* __restrict__ bias,
                                               const float* __restrict__ res,
                                               float* __restrict__ outF,
                                               unsigned short* __restrict__ outB,
                                               int M, int N, int K) {
  __shared__ __align__(16) unsigned short As[128 * 32];
  __shared__ __align__(16) unsigned short Bs[128 * 32];
  const int tid = threadIdx.x;
  const int w = tid >> 6, lane = tid & 63;
  const int l15 = lane & 15, l4 = lane >> 4;
  const int rowBase = blockIdx.y * 128, colBase = blockIdx.x * 128;
  const int wm = w >> 1, wn = w & 1;

  f32x4 acc[4][4] = {};

  const int c0 = w * 64 + lane;
  const int c1 = 256 + c0;

  for (int k0 = 0; k0 < K; k0 += 32) {
    const unsigned short* ga0 = A + (size_t)(rowBase + (c0 >> 2)) * K + k0 + ((c0 & 3) << 3);
    const unsigned short* ga1 = A + (size_t)(rowBase + (c1 >> 2)) * K + k0 + ((c1 & 3) << 3);
    GLOAD_LDS16(ga0, As + w * 512);
    GLOAD_LDS16(ga1, As + 2048 + w * 512);
    const unsigned short* gb0 = B + (size_t)(colBase + (c0 >> 2)) * K + k0 + ((c0 & 3) << 3);
    const unsigned short* gb1 = B + (size_t)(colBase + (c1 >> 2)) * K + k0 + ((c1 & 3) << 3);
    GLOAD_LDS16(gb0, Bs + w * 512);
    GLOAD_LDS16(gb1, Bs + 2048 + w * 512);
    __syncthreads();

    short8 af[4], bf[4];
#pragma unroll
    for (int f = 0; f < 4; ++f) {
      af[f] = *(const short8*)(As + (wm * 64 + f * 16 + l15) * 32 + l4 * 8);
      bf[f] = *(const short8*)(Bs + (wn * 64 + f * 16 + l15) * 32 + l4 * 8);
    }
#pragma unroll
    for (int i = 0; i < 4; ++i)
#pragma unroll
      for (int j = 0; j < 4; ++j)
        acc[i][j] = MFMA16(af[i], bf[j], acc[i][j]);
    __syncthreads();
  }

#pragma unroll
  for (int i = 0; i < 4; ++i) {
    const int row0 = rowBase + wm * 64 + i * 16 + l4 * 4;
#pragma unroll
    for (int j = 0; j < 4; ++j) {
      const int col = colBase + wn * 64 + j * 16 + l15;
      const float bv = bias[col];
#pragma unroll
      for (int e = 0; e < 4; ++e) {
        const int row = row0 + e;
        float v = acc[i][j][e] + bv;
        if constexpr (RELU) v = fmaxf(v, 0.f);
        if constexpr (RES) v += res[(size_t)row * N + col];
        if constexpr (OUTF) outF[(size_t)row * N + col] = v;
        if constexpr (OUTB) outB[(size_t)row * N + col] = f2bf(v);
      }
    }
  }
}

// ---------------------------------------------------------------------------
// V transpose: vt[c][r] = qkv[r][2048+c], c in [0,1024), r in [0,N)
// ---------------------------------------------------------------------------
__global__ __launch_bounds__(256) void transpose_v(const unsigned short* __restrict__ qkv,
                                                   unsigned short* __restrict__ vt, int Nseq) {
  __shared__ unsigned short T[64][72];
  const int r0 = blockIdx.x * 64;   // k rows
  const int c0 = blockIdx.y * 64;   // v cols
  const int tid = threadIdx.x;
#pragma unroll
  for (int i = 0; i < 2; ++i) {
    int c = tid * 2 + i;
    int r = c >> 3, off = (c & 7) * 8;
    short8 v = *(const short8*)(qkv + (size_t)(r0 + r) * 3072 + 2048 + c0 + off);
    *(short8*)(&T[r][off]) = v;
  }
  __syncthreads();
#pragma unroll
  for (int i = 0; i < 2; ++i) {
    int c = tid * 2 + i;
    int orow = c >> 3, off = (c & 7) * 8;
    short8 v;
#pragma unroll
    for (int e = 0; e < 8; ++e) v[e] = T[off + e][orow];
    *(short8*)(vt + (size_t)(c0 + orow) * Nseq + r0 + off) = v;
  }
}

// ---------------------------------------------------------------------------
// Flash attention v4: 32x32x16 MFMA, in-register softmax + P (cvt_pk +
// permlane32_swap), XOR-swizzled [64][64] K/Vt LDS tiles, dbuf staging,
// KSPLIT=4 over keys.  4 waves x 32 q-rows = 128 q/block.
// Lane owns q = q0w + (lane&31); S^T acc: key = (reg&3)+8*(reg>>2)+4*(lane>>5)+sub*32.
// ---------------------------------------------------------------------------
__global__ __launch_bounds__(256, 3) void flash_attn4(const unsigned short* __restrict__ qkv,
                                                      const unsigned short* __restrict__ vt,
                                                      float* __restrict__ Op0,
                                                      float* __restrict__ OpR,
                                                      float* __restrict__ Ml,
                                                      float* __restrict__ Ll,
                                                      int Nseq) {
  __shared__ __align__(16) unsigned short Ks[2][64 * 64];
  __shared__ __align__(16) unsigned short Vs[2][64 * 64];
  const int tid = threadIdx.x, w = tid >> 6, lane = tid & 63;
  const int l31 = lane & 31, l2h = lane >> 5, l7 = l31 & 7;
  const float CSC = 0.18033688011112042f;   // 0.125 * log2(e)

  // 1024 blocks: head pinned to XCD (b&7); s = key split; qb = q tile
  const int b = blockIdx.x;
  const int head = (b & 7) * 2 + ((b >> 3) & 1);
  const int s = (b >> 4) & 3;
  const int qb = b >> 6;
  const int q0w = qb * 128 + w * 32;

  const unsigned short* Qp = qkv + head * 64;
  const unsigned short* Kp = qkv + 1024 + head * 64;
  const unsigned short* Vtp = vt + (size_t)head * 64 * Nseq;

  // Q frags (B-operand): lane supplies Q[q0w+l31][kappa*16 + l2h*8 + j]
  short8 qf[4];
#pragma unroll
  for (int ka = 0; ka < 4; ++ka)
    qf[ka] = *(const short8*)(Qp + (size_t)(q0w + l31) * 3072 + ka * 16 + l2h * 8);

  f32x16 OT0 = {}, OT1 = {};
  float m = -1e30f, ls = 0.f;

  // staging geometry (XOR swizzle on 16B units)
  const int sr = tid >> 3, su = tid & 7;
  const int sOffA = sr * 64 + ((su ^ (sr & 7)) * 8);
  const int sOffB = sOffA + 32 * 64;

  const int kt0 = s * (Nseq >> 2);
  const int NIT = Nseq >> 8;   // (Nseq/4)/64

  // prologue: stage tile 0
  short8 k0 = *(const short8*)(Kp + (size_t)(kt0 + sr) * 3072 + su * 8);
  short8 k1 = *(const short8*)(Kp + (size_t)(kt0 + sr + 32) * 3072 + su * 8);
  short8 v0 = *(const short8*)(Vtp + (size_t)sr * Nseq + kt0 + su * 8);
  short8 v1 = *(const short8*)(Vtp + (size_t)(sr + 32) * Nseq + kt0 + su * 8);
  *(short8*)(Ks[0] + sOffA) = k0;
  *(short8*)(Ks[0] + sOffB) = k1;
  *(short8*)(Vs[0] + sOffA) = v0;
  *(short8*)(Vs[0] + sOffB) = v1;
  __syncthreads();

  int p = 0;
  for (int it = 0; it < NIT; ++it) {
    const bool more = (it + 1) < NIT;
    if (more) {   // issue next-tile loads early (T14)
      const int ktn = kt0 + (it + 1) * 64;
      k0 = *(const short8*)(Kp + (size_t)(ktn + sr) * 3072 + su * 8);
      k1 = *(const short8*)(Kp + (size_t)(ktn + sr + 32) * 3072 + su * 8);
      v0 = *(const short8*)(Vtp + (size_t)sr * Nseq + ktn + su * 8);
      v1 = *(const short8*)(Vtp + (size_t)(sr + 32) * Nseq + ktn + su * 8);
    }
    const unsigned short* KS = Ks[p];
    const unsigned short* VS = Vs[p];

    // ---- QK^T: S^T[key][q], two 32-key subtiles
    f32x16 S0 = {}, S1 = {};
#pragma unroll
    for (int ka = 0; ka < 4; ++ka) {
      const int un = ((ka * 2 + l2h) ^ l7) * 8;
      const short8 a0 = *(const short8*)(KS + l31 * 64 + un);
      const short8 a1 = *(const short8*)(KS + (32 + l31) * 64 + un);
      S0 = MFMA32(a0, qf[ka], S0);
      S1 = MFMA32(a1, qf[ka], S1);
    }

    // ---- row max (lane owns one q; partner holds other 32 keys)
    float pm = S0[0];
#pragma unroll
    for (int r = 1; r < 16; ++r) pm = fmaxf(pm, S0[r]);
#pragma unroll
    for (int r = 0; r < 16; ++r) pm = fmaxf(pm, S1[r]);
    pm = fmaxf(pm, __shfl_xor(pm, 32));
    pm *= CSC;

    // defer-max rescale (threshold 8 in exp2 domain)
    if (__any(pm > m + 8.f)) {
      const float mn = fmaxf(m, pm);
      const float fac = EXP2(m - mn);
      m = mn;
      ls *= fac;
#pragma unroll
      for (int r = 0; r < 16; ++r) { OT0[r] *= fac; OT1[r] *= fac; }
    }

    // ---- P = exp2(S*CSC - m); pack to bf16 words W[sub][g][pw]
    float rs = 0.f;
    unsigned W0[4][2], W1[4][2];
#pragma unroll
    for (int g = 0; g < 4; ++g) {
      const float a0 = EXP2(fmaf(S0[4 * g + 0], CSC, -m));
      const float a1 = EXP2(fmaf(S0[4 * g + 1], CSC, -m));
      const float a2 = EXP2(fmaf(S0[4 * g + 2], CSC, -m));
      const float a3 = EXP2(fmaf(S0[4 * g + 3], CSC, -m));
      const float b0 = EXP2(fmaf(S1[4 * g + 0], CSC, -m));
      const float b1 = EXP2(fmaf(S1[4 * g + 1], CSC, -m));
      const float b2 = EXP2(fmaf(S1[4 * g + 2], CSC, -m));
      const float b3 = EXP2(fmaf(S1[4 * g + 3], CSC, -m));
      rs += ((a0 + a1) + (a2 + a3)) + ((b0 + b1) + (b2 + b3));
      W0[g][0] = cvtpk(a0, a1); W0[g][1] = cvtpk(a2, a3);
      W1[g][0] = cvtpk(b0, b1); W1[g][1] = cvtpk(b2, b3);
    }
    rs += __shfl_xor(rs, 32);
    ls += rs;

    // ---- exchange halves -> PV B-frags pf[sub][kappa]
    short8 pf[2][2];
#pragma unroll
    for (int ka = 0; ka < 2; ++ka) {
      {
        unsigned x0 = W0[2 * ka][0], y0 = W0[2 * ka + 1][0];
        unsigned x1 = W0[2 * ka][1], y1 = W0[2 * ka + 1][1];
        swap32(x0, y0);
        swap32(x1, y1);
        uint4v u = {x0, x1, y0, y1};
        pf[0][ka] = __builtin_bit_cast(short8, u);
      }
      {
        unsigned x0 = W1[2 * ka][0], y0 = W1[2 * ka + 1][0];
        unsigned x1 = W1[2 * ka][1], y1 = W1[2 * ka + 1][1];
        swap32(x0, y0);
        swap32(x1, y1);
        uint4v u = {x0, x1, y0, y1};
        pf[1][ka] = __builtin_bit_cast(short8, u);
      }
    }

    // ---- O^T += V^T x P^T  (A = Vt rows d, B = P frags)
#pragma unroll
    for (int sub = 0; sub < 2; ++sub)
#pragma unroll
      for (int ka = 0; ka < 2; ++ka) {
        const int un = ((sub * 4 + ka * 2 + l2h) ^ l7) * 8;
        const short8 va0 = *(const short8*)(VS + l31 * 64 + un);
        const short8 va1 = *(const short8*)(VS + (32 + l31) * 64 + un);
        OT0 = MFMA32(va0, pf[sub][ka], OT0);
        OT1 = MFMA32(va1, pf[sub][ka], OT1);
      }

    if (more) {
      unsigned short* Kn = Ks[p ^ 1];
      unsigned short* Vn = Vs[p ^ 1];
      *(short8*)(Kn + sOffA) = k0;
      *(short8*)(Kn + sOffB) = k1;
      *(short8*)(Vn + sOffA) = v0;
      *(short8*)(Vn + sOffB) = v1;
    }
    __syncthreads();
    p ^= 1;
  }

  // ---- epilogue: write un-normalized O^T partials + (m, ls)
  float* Ob = (s == 0) ? Op0 : (OpR + (size_t)(s - 1) * Nseq * 1024);
  const int q = q0w + l31;
#pragma unroll
  for (int g = 0; g < 4; ++g) {
    const int d0 = 8 * g + 4 * l2h;
    float4v t0 = {OT0[4 * g], OT0[4 * g + 1], OT0[4 * g + 2], OT0[4 * g + 3]};
    float4v t1 = {OT1[4 * g], OT1[4 * g + 1], OT1[4 * g + 2], OT1[4 * g + 3]};
    *(float4v*)(Ob + (size_t)q * 1024 + head * 64 + d0) = t0;
    *(float4v*)(Ob + (size_t)q * 1024 + head * 64 + 32 + d0) = t1;
  }
  if (l2h == 0) {
    Ml[(size_t)(s * 16 + head) * Nseq + q] = m;
    Ll[(size_t)(s * 16 + head) * Nseq + q] = ls;
  }
}

// ---------------------------------------------------------------------------
// Combine the 4 key-split partials (exp2 domain) -> bf16 attention output
// ---------------------------------------------------------------------------
__global__ __launch_bounds__(256) void attn_combine4(const float* __restrict__ Op0,
                                                     const float* __restrict__ OpR,
                                                     const float* __restrict__ Ml,
                                                     const float* __restrict__ Ll,
                                                     unsigned short* __restrict__ out, int Nseq) {
  const int t = blockIdx.x * 256 + threadIdx.x;
  const int q = t >> 8, c4 = (t & 255) * 4;
  const int head = c4 >> 6;
  float mm[4], lv[4];
  float M = -1e30f;
#pragma unroll
  for (int s = 0; s < 4; ++s) {
    mm[s] = Ml[(size_t)(s * 16 + head) * Nseq + q];
    lv[s] = Ll[(size_t)(s * 16 + head) * Nseq + q];
    M = fmaxf(M, mm[s]);
  }
  float denom = 0.f;
  float4v acc = {0.f, 0.f, 0.f, 0.f};
#pragma unroll
  for (int s = 0; s < 4; ++s) {
    const float ww = EXP2(mm[s] - M);
    denom += lv[s] * ww;
    const float* Ob = (s == 0) ? Op0 : (OpR + (size_t)(s - 1) * Nseq * 1024);
    float4v o = *(const float4v*)(Ob + (size_t)q * 1024 + c4);
    acc.x += o.x * ww; acc.y += o.y * ww; acc.z += o.z * ww; acc.w += o.w * ww;
  }
  const float inv = 1.f / denom;
  ushort4v r;
  r.x = f2bf(acc.x * inv);
  r.y = f2bf(acc.y * inv);
  r.z = f2bf(acc.z * inv);
  r.w = f2bf(acc.w * inv);
  *(ushort4v*)(out + (size_t)q * 1024 + c4) = r;
}

// ---------------------------------------------------------------------------
// Row LayerNorm (two-pass, fp32).  One block (256 thr) per row.
// ---------------------------------------------------------------------------
template <int D>
__global__ __launch_bounds__(256) void ln_rows(const float* __restrict__ src,
                                               const float* __restrict__ gw,
                                               const float* __restrict__ bw,
                                               float* __restrict__ outF,
                                               unsigned short* __restrict__ outB) {
  __shared__ float red[4];
  const int row = blockIdx.x;
  const int tid = threadIdx.x, w = tid >> 6;
  constexpr int PT = D / 256;
  const float* r = src + (size_t)row * D;
  float v[PT];
  float s = 0.f;
#pragma unroll
  for (int i = 0; i < PT; ++i) { v[i] = r[tid + i * 256]; s += v[i]; }
#pragma unroll
  for (int off = 32; off; off >>= 1) s += __shfl_down(s, off);
  if ((tid & 63) == 0) red[w] = s;
  __syncthreads();
  const float mean = (red[0] + red[1] + red[2] + red[3]) / D;
  __syncthreads();
  float q = 0.f;
#pragma unroll
  for (int i = 0; i < PT; ++i) { const float d = v[i] - mean; q += d * d; }
#pragma unroll
  for (int off = 32; off; off >>= 1) q += __shfl_down(q, off);
  if ((tid & 63) == 0) red[w] = q;
  __syncthreads();
  const float rstd = rsqrtf((red[0] + red[1] + red[2] + red[3]) / D + 1e-5f);
#pragma unroll
  for (int i = 0; i < PT; ++i) {
    const int c = tid + i * 256;
    const float o = (v[i] - mean) * rstd * gw[c] + bw[c];
    outF[(size_t)row * D + c] = o;
    if (outB) outB[(size_t)row * D + c] = f2bf(o);
  }
}

// ---------------------------------------------------------------------------
// Orchestration
// ---------------------------------------------------------------------------
extern "C" void kernel_launch(void* const* d_in, const int* in_sizes, int n_in,
                              void* d_out, int out_size, void* d_ws, size_t ws_size,
                              hipStream_t stream) {
  const int N = 2048, D_IN = 512, H = 1024, D_OUT = 256, NL = 4;
  const float* x    = (const float*)d_in[0];
  const float* W1   = (const float*)d_in[1];
  const float* b1   = (const float*)d_in[2];
  const float* Wqkv = (const float*)d_in[3];
  const float* bqkv = (const float*)d_in[4];
  const float* Wo   = (const float*)d_in[5];
  const float* bo   = (const float*)d_in[6];
  const float* lng  = (const float*)d_in[7];
  const float* lnb  = (const float*)d_in[8];
  const float* W2   = (const float*)d_in[9];
  const float* b2   = (const float*)d_in[10];
  const float* gout = (const float*)d_in[11];
  const float* bout = (const float*)d_in[12];
  float* out = (float*)d_out;

  char* ws = (char*)d_ws;
  auto alloc = [&](size_t bytes) -> char* {
    char* p = ws;
    ws += (bytes + 255) & ~(size_t)255;
    return p;
  };
  unsigned short* xb    = (unsigned short*)alloc((size_t)N * D_IN * 2);
  unsigned short* W1b   = (unsigned short*)alloc((size_t)H * D_IN * 2);
  unsigned short* Wqkvb = (unsigned short*)alloc((size_t)NL * 3 * H * H * 2);
  unsigned short* Wob   = (unsigned short*)alloc((size_t)NL * H * H * 2);
  unsigned short* W2b   = (unsigned short*)alloc((size_t)D_OUT * H * 2);
  unsigned short* hb    = (unsigned short*)alloc((size_t)N * H * 2);
  unsigned short* qkvb  = (unsigned short*)alloc((size_t)N * 3 * H * 2);
  unsigned short* aob   = (unsigned short*)alloc((size_t)N * H * 2);
  unsigned short* vtg   = (unsigned short*)alloc((size_t)H * N * 2);
  float* hf  = (float*)alloc((size_t)N * H * 4);
  float* af  = (float*)alloc((size_t)N * H * 4);   // aliased as attn partial Op0
  float* opR = (float*)alloc((size_t)3 * N * H * 4);
  float* ml  = (float*)alloc((size_t)4 * 16 * N * 4);
  float* ll  = (float*)alloc((size_t)4 * 16 * N * 4);
  float* yf  = (float*)alloc((size_t)N * D_OUT * 4);
  float* op0 = af;  // safe: combine consumes op0 before o-proj writes af

  auto cvt = [&](const float* s, unsigned short* d, int n) {
    int blocks = (n / 4 + 255) / 256;
    if (blocks > 2048) blocks = 2048;
    cvt_bf16<<<blocks, 256, 0, stream>>>(s, d, n);
  };
  cvt(x, xb, N * D_IN);
  cvt(W1, W1b, H * D_IN);
  cvt(Wqkv, Wqkvb, NL * 3 * H * H);
  cvt(Wo, Wob, NL * H * H);
  cvt(W2, W2b, D_OUT * H);

  // FC1: h = relu(x @ W1^T + b1) -> hf, hb
  gemm_bt<true, false, true, true><<<dim3(H / 128, N / 128), 256, 0, stream>>>(
      xb, W1b, b1, nullptr, hf, hb, N, H, D_IN);

  for (int l = 0; l < NL; ++l) {
    gemm_bt<false, false, false, true><<<dim3(3 * H / 128, N / 128), 256, 0, stream>>>(
        hb, Wqkvb + (size_t)l * 3 * H * H, bqkv + (size_t)l * 3 * H, nullptr, nullptr, qkvb,
        N, 3 * H, H);
    transpose_v<<<dim3(N / 64, H / 64), 256, 0, stream>>>(qkvb, vtg, N);
    flash_attn4<<<1024, 256, 0, stream>>>(qkvb, vtg, op0, opR, ml, ll, N);
    attn_combine4<<<(N * H / 4) / 256, 256, 0, stream>>>(op0, opR, ml, ll, aob, N);
    gemm_bt<false, true, true, false><<<dim3(H / 128, N / 128), 256, 0, stream>>>(
        aob, Wob + (size_t)l * H * H, bo + (size_t)l * H, hf, af, nullptr, N, H, H);
    ln_rows<1024><<<N, 256, 0, stream>>>(af, lng + (size_t)l * H, lnb + (size_t)l * H, hf, hb);
  }

  gemm_bt<true, false, true, false><<<dim3(D_OUT / 128, N / 128), 256, 0, stream>>>(
      hb, W2b, b2, nullptr, yf, nullptr, N, D_OUT, H);
  ln_rows<256><<<N, 256, 0, stream>>>(yf, gout, bout, out, nullptr);
}

// Round 5
// 423.347 us; speedup vs baseline: 1.7982x; 1.1444x over previous
//
#include <hip/hip_runtime.h>

// ---------------------------------------------------------------------------
// Types / helpers
// ---------------------------------------------------------------------------
typedef __attribute__((ext_vector_type(8))) short short8;      // 8 bf16
typedef __attribute__((ext_vector_type(4))) float f32x4;
typedef __attribute__((ext_vector_type(16))) float f32x16;     // 32x32 mfma acc
typedef __attribute__((ext_vector_type(4))) float float4v;
typedef __attribute__((ext_vector_type(4))) unsigned short ushort4v;
typedef __attribute__((ext_vector_type(4))) unsigned int uint4v;

#define MFMA16(a, b, c) __builtin_amdgcn_mfma_f32_16x16x32_bf16((a), (b), (c), 0, 0, 0)
#define MFMA32(a, b, c) __builtin_amdgcn_mfma_f32_32x32x16_bf16((a), (b), (c), 0, 0, 0)
#define GLOAD_LDS16(g, s)                                                         \
  __builtin_amdgcn_global_load_lds((const __attribute__((address_space(1))) void*)(g), \
                                   (__attribute__((address_space(3))) void*)(s), 16, 0, 0)
#define EXP2(x) __builtin_amdgcn_exp2f(x)

__device__ __forceinline__ unsigned short f2bf(float f) {
  unsigned u = __builtin_bit_cast(unsigned, f);
  u += 0x7fffu + ((u >> 16) & 1u);   // round-to-nearest-even
  return (unsigned short)(u >> 16);
}

__device__ __forceinline__ unsigned cvtpk(float lo, float hi) {
  unsigned r;
  asm("v_cvt_pk_bf16_f32 %0, %1, %2" : "=v"(r) : "v"(lo), "v"(hi));
  return r;
}

// v_permlane32_swap_b32 a, b: a[32:63] <-> b[0:31]
__device__ __forceinline__ void swap32(unsigned& a, unsigned& b) {
  asm volatile("v_permlane32_swap_b32 %0, %1" : "+v"(a), "+v"(b));
}

// ---------------------------------------------------------------------------
// Fused fp32 -> bf16 convert for all 5 weight/input arrays (1 launch)
// ---------------------------------------------------------------------------
struct CvtArgs {
  const float* s[5];
  unsigned short* d[5];
  int off[6];   // cumulative element offsets (all multiples of 4)
};

__global__ __launch_bounds__(256) void cvt_multi(CvtArgs a, int ntot4) {
  int i4 = blockIdx.x * 256 + threadIdx.x;
  const int stride = gridDim.x * 256;
  for (; i4 < ntot4; i4 += stride) {
    const int idx = i4 * 4;
    int s = 0;
#pragma unroll
    for (int k = 0; k < 4; ++k) s += (idx >= a.off[k + 1]) ? 1 : 0;
    const int local = idx - a.off[s];
    float4v v = *(const float4v*)(a.s[s] + local);
    ushort4v o;
    o.x = f2bf(v.x); o.y = f2bf(v.y); o.z = f2bf(v.z); o.w = f2bf(v.w);
    *(ushort4v*)(a.d[s] + local) = o;
  }
}

// ---------------------------------------------------------------------------
// GEMM: C[M][N] = act(A[M][K] @ B[N][K]^T + bias[N]) (+ residual)
// 128x128 tile, BK=32, 2-phase double-buffered LDS pipeline (1 barrier/K-step).
// OUTT: additionally write C^T for cols >= tcol0 (V^T production for attn).
// ---------------------------------------------------------------------------
template <bool RELU, bool RES, bool OUTF, bool OUTB, bool OUTT>
__global__ __launch_bounds__(256) void gemm_bt(const unsigned short* __restrict__ A,
                                               const unsigned short* __restrict__ B,
                                               const float* __restrict__ bias,
                                               const float* __restrict__ res,
                                               float* __restrict__ outF,
                                               unsigned short* __restrict__ outB,
                                               unsigned short* __restrict__ outT,
                                               int tcol0, int ldt,
                                               int M, int N, int K) {
  __shared__ __align__(16) unsigned short As[2][128 * 32];
  __shared__ __align__(16) unsigned short Bs[2][128 * 32];
  const int tid = threadIdx.x;
  const int w = tid >> 6, lane = tid & 63;
  const int l15 = lane & 15, l4 = lane >> 4;
  const int rowBase = blockIdx.y * 128, colBase = blockIdx.x * 128;
  const int wm = w >> 1, wn = w & 1;

  f32x4 acc[4][4] = {};

  const int c0 = w * 64 + lane;     // staging chunk ids (16B each)
  const int c1 = 256 + c0;
  const int ra0 = c0 >> 2, ka0 = (c0 & 3) << 3;
  const int ra1 = c1 >> 2, ka1 = (c1 & 3) << 3;

  auto stage = [&](int buf, int k0) {
    GLOAD_LDS16(A + (size_t)(rowBase + ra0) * K + k0 + ka0, As[buf] + w * 512);
    GLOAD_LDS16(A + (size_t)(rowBase + ra1) * K + k0 + ka1, As[buf] + 2048 + w * 512);
    GLOAD_LDS16(B + (size_t)(colBase + ra0) * K + k0 + ka0, Bs[buf] + w * 512);
    GLOAD_LDS16(B + (size_t)(colBase + ra1) * K + k0 + ka1, Bs[buf] + 2048 + w * 512);
  };

  stage(0, 0);
  __syncthreads();

  int p = 0;
  for (int k0 = 0; k0 < K; k0 += 32) {
    if (k0 + 32 < K) stage(p ^ 1, k0 + 32);   // issue next tile early

    short8 af[4], bf[4];
#pragma unroll
    for (int f = 0; f < 4; ++f) {
      af[f] = *(const short8*)(As[p] + (wm * 64 + f * 16 + l15) * 32 + l4 * 8);
      bf[f] = *(const short8*)(Bs[p] + (wn * 64 + f * 16 + l15) * 32 + l4 * 8);
    }
#pragma unroll
    for (int i = 0; i < 4; ++i)
#pragma unroll
      for (int j = 0; j < 4; ++j)
        acc[i][j] = MFMA16(af[i], bf[j], acc[i][j]);

    __syncthreads();   // drains vmcnt: next buffer staged; all reads of p done
    p ^= 1;
  }

#pragma unroll
  for (int i = 0; i < 4; ++i) {
    const int row0 = rowBase + wm * 64 + i * 16 + l4 * 4;
#pragma unroll
    for (int j = 0; j < 4; ++j) {
      const int col = colBase + wn * 64 + j * 16 + l15;
      const float bv = bias[col];
      float vv[4];
#pragma unroll
      for (int e = 0; e < 4; ++e) {
        float v = acc[i][j][e] + bv;
        if constexpr (RELU) v = fmaxf(v, 0.f);
        if constexpr (RES) v += res[(size_t)(row0 + e) * N + col];
        vv[e] = v;
        if constexpr (OUTF) outF[(size_t)(row0 + e) * N + col] = v;
        if constexpr (OUTB) outB[(size_t)(row0 + e) * N + col] = f2bf(v);
      }
      if constexpr (OUTT) {
        if (col >= tcol0) {
          ushort4v t;
          t.x = f2bf(vv[0]); t.y = f2bf(vv[1]); t.z = f2bf(vv[2]); t.w = f2bf(vv[3]);
          *(ushort4v*)(outT + (size_t)(col - tcol0) * ldt + row0) = t;
        }
      }
    }
  }
}

// ---------------------------------------------------------------------------
// Flash attention v4: 32x32x16 MFMA, in-register softmax + P (cvt_pk +
// permlane32_swap), XOR-swizzled [64][64] K/Vt LDS tiles, dbuf staging,
// KSPLIT=4 over keys.  4 waves x 32 q-rows = 128 q/block.
// ---------------------------------------------------------------------------
__global__ __launch_bounds__(256, 3) void flash_attn4(const unsigned short* __restrict__ qkv,
                                                      const unsigned short* __restrict__ vt,
                                                      float* __restrict__ Op0,
                                                      float* __restrict__ OpR,
                                                      float* __restrict__ Ml,
                                                      float* __restrict__ Ll,
                                                      int Nseq) {
  __shared__ __align__(16) unsigned short Ks[2][64 * 64];
  __shared__ __align__(16) unsigned short Vs[2][64 * 64];
  const int tid = threadIdx.x, w = tid >> 6, lane = tid & 63;
  const int l31 = lane & 31, l2h = lane >> 5, l7 = l31 & 7;
  const float CSC = 0.18033688011112042f;   // 0.125 * log2(e)

  const int b = blockIdx.x;
  const int head = (b & 7) * 2 + ((b >> 3) & 1);
  const int s = (b >> 4) & 3;
  const int qb = b >> 6;
  const int q0w = qb * 128 + w * 32;

  const unsigned short* Qp = qkv + head * 64;
  const unsigned short* Kp = qkv + 1024 + head * 64;
  const unsigned short* Vtp = vt + (size_t)head * 64 * Nseq;

  short8 qf[4];
#pragma unroll
  for (int ka = 0; ka < 4; ++ka)
    qf[ka] = *(const short8*)(Qp + (size_t)(q0w + l31) * 3072 + ka * 16 + l2h * 8);

  f32x16 OT0 = {}, OT1 = {};
  float m = -1e30f, ls = 0.f;

  const int sr = tid >> 3, su = tid & 7;
  const int sOffA = sr * 64 + ((su ^ (sr & 7)) * 8);
  const int sOffB = sOffA + 32 * 64;

  const int kt0 = s * (Nseq >> 2);
  const int NIT = Nseq >> 8;   // (Nseq/4)/64

  short8 k0 = *(const short8*)(Kp + (size_t)(kt0 + sr) * 3072 + su * 8);
  short8 k1 = *(const short8*)(Kp + (size_t)(kt0 + sr + 32) * 3072 + su * 8);
  short8 v0 = *(const short8*)(Vtp + (size_t)sr * Nseq + kt0 + su * 8);
  short8 v1 = *(const short8*)(Vtp + (size_t)(sr + 32) * Nseq + kt0 + su * 8);
  *(short8*)(Ks[0] + sOffA) = k0;
  *(short8*)(Ks[0] + sOffB) = k1;
  *(short8*)(Vs[0] + sOffA) = v0;
  *(short8*)(Vs[0] + sOffB) = v1;
  __syncthreads();

  int p = 0;
  for (int it = 0; it < NIT; ++it) {
    const bool more = (it + 1) < NIT;
    if (more) {   // issue next-tile loads early (T14)
      const int ktn = kt0 + (it + 1) * 64;
      k0 = *(const short8*)(Kp + (size_t)(ktn + sr) * 3072 + su * 8);
      k1 = *(const short8*)(Kp + (size_t)(ktn + sr + 32) * 3072 + su * 8);
      v0 = *(const short8*)(Vtp + (size_t)sr * Nseq + ktn + su * 8);
      v1 = *(const short8*)(Vtp + (size_t)(sr + 32) * Nseq + ktn + su * 8);
    }
    const unsigned short* KS = Ks[p];
    const unsigned short* VS = Vs[p];

    // ---- QK^T: S^T[key][q]
    f32x16 S0 = {}, S1 = {};
    __builtin_amdgcn_s_setprio(1);
#pragma unroll
    for (int ka = 0; ka < 4; ++ka) {
      const int un = ((ka * 2 + l2h) ^ l7) * 8;
      const short8 a0 = *(const short8*)(KS + l31 * 64 + un);
      const short8 a1 = *(const short8*)(KS + (32 + l31) * 64 + un);
      S0 = MFMA32(a0, qf[ka], S0);
      S1 = MFMA32(a1, qf[ka], S1);
    }
    __builtin_amdgcn_s_setprio(0);

    // ---- row max
    float pm = S0[0];
#pragma unroll
    for (int r = 1; r < 16; ++r) pm = fmaxf(pm, S0[r]);
#pragma unroll
    for (int r = 0; r < 16; ++r) pm = fmaxf(pm, S1[r]);
    pm = fmaxf(pm, __shfl_xor(pm, 32));
    pm *= CSC;

    // defer-max rescale (threshold 8 in exp2 domain)
    if (__any(pm > m + 8.f)) {
      const float mn = fmaxf(m, pm);
      const float fac = EXP2(m - mn);
      m = mn;
      ls *= fac;
#pragma unroll
      for (int r = 0; r < 16; ++r) { OT0[r] *= fac; OT1[r] *= fac; }
    }

    // ---- P = exp2(S*CSC - m); pack to bf16 words
    float rs = 0.f;
    unsigned W0[4][2], W1[4][2];
#pragma unroll
    for (int g = 0; g < 4; ++g) {
      const float a0 = EXP2(fmaf(S0[4 * g + 0], CSC, -m));
      const float a1 = EXP2(fmaf(S0[4 * g + 1], CSC, -m));
      const float a2 = EXP2(fmaf(S0[4 * g + 2], CSC, -m));
      const float a3 = EXP2(fmaf(S0[4 * g + 3], CSC, -m));
      const float b0 = EXP2(fmaf(S1[4 * g + 0], CSC, -m));
      const float b1 = EXP2(fmaf(S1[4 * g + 1], CSC, -m));
      const float b2 = EXP2(fmaf(S1[4 * g + 2], CSC, -m));
      const float b3 = EXP2(fmaf(S1[4 * g + 3], CSC, -m));
      rs += ((a0 + a1) + (a2 + a3)) + ((b0 + b1) + (b2 + b3));
      W0[g][0] = cvtpk(a0, a1); W0[g][1] = cvtpk(a2, a3);
      W1[g][0] = cvtpk(b0, b1); W1[g][1] = cvtpk(b2, b3);
    }
    rs += __shfl_xor(rs, 32);
    ls += rs;

    // ---- exchange halves -> PV B-frags
    short8 pf[2][2];
#pragma unroll
    for (int ka = 0; ka < 2; ++ka) {
      {
        unsigned x0 = W0[2 * ka][0], y0 = W0[2 * ka + 1][0];
        unsigned x1 = W0[2 * ka][1], y1 = W0[2 * ka + 1][1];
        swap32(x0, y0);
        swap32(x1, y1);
        uint4v u = {x0, x1, y0, y1};
        pf[0][ka] = __builtin_bit_cast(short8, u);
      }
      {
        unsigned x0 = W1[2 * ka][0], y0 = W1[2 * ka + 1][0];
        unsigned x1 = W1[2 * ka][1], y1 = W1[2 * ka + 1][1];
        swap32(x0, y0);
        swap32(x1, y1);
        uint4v u = {x0, x1, y0, y1};
        pf[1][ka] = __builtin_bit_cast(short8, u);
      }
    }

    // ---- O^T += V^T x P^T
    __builtin_amdgcn_s_setprio(1);
#pragma unroll
    for (int sub = 0; sub < 2; ++sub)
#pragma unroll
      for (int ka = 0; ka < 2; ++ka) {
        const int un = ((sub * 4 + ka * 2 + l2h) ^ l7) * 8;
        const short8 va0 = *(const short8*)(VS + l31 * 64 + un);
        const short8 va1 = *(const short8*)(VS + (32 + l31) * 64 + un);
        OT0 = MFMA32(va0, pf[sub][ka], OT0);
        OT1 = MFMA32(va1, pf[sub][ka], OT1);
      }
    __builtin_amdgcn_s_setprio(0);

    if (more) {
      unsigned short* Kn = Ks[p ^ 1];
      unsigned short* Vn = Vs[p ^ 1];
      *(short8*)(Kn + sOffA) = k0;
      *(short8*)(Kn + sOffB) = k1;
      *(short8*)(Vn + sOffA) = v0;
      *(short8*)(Vn + sOffB) = v1;
    }
    __syncthreads();
    p ^= 1;
  }

  float* Ob = (s == 0) ? Op0 : (OpR + (size_t)(s - 1) * Nseq * 1024);
  const int q = q0w + l31;
#pragma unroll
  for (int g = 0; g < 4; ++g) {
    const int d0 = 8 * g + 4 * l2h;
    float4v t0 = {OT0[4 * g], OT0[4 * g + 1], OT0[4 * g + 2], OT0[4 * g + 3]};
    float4v t1 = {OT1[4 * g], OT1[4 * g + 1], OT1[4 * g + 2], OT1[4 * g + 3]};
    *(float4v*)(Ob + (size_t)q * 1024 + head * 64 + d0) = t0;
    *(float4v*)(Ob + (size_t)q * 1024 + head * 64 + 32 + d0) = t1;
  }
  if (l2h == 0) {
    Ml[(size_t)(s * 16 + head) * Nseq + q] = m;
    Ll[(size_t)(s * 16 + head) * Nseq + q] = ls;
  }
}

// ---------------------------------------------------------------------------
// Combine the 4 key-split partials (exp2 domain) -> bf16 attention output
// ---------------------------------------------------------------------------
__global__ __launch_bounds__(256) void attn_combine4(const float* __restrict__ Op0,
                                                     const float* __restrict__ OpR,
                                                     const float* __restrict__ Ml,
                                                     const float* __restrict__ Ll,
                                                     unsigned short* __restrict__ out, int Nseq) {
  const int t = blockIdx.x * 256 + threadIdx.x;
  const int q = t >> 8, c4 = (t & 255) * 4;
  const int head = c4 >> 6;
  float mm[4], lv[4];
  float M = -1e30f;
#pragma unroll
  for (int s = 0; s < 4; ++s) {
    mm[s] = Ml[(size_t)(s * 16 + head) * Nseq + q];
    lv[s] = Ll[(size_t)(s * 16 + head) * Nseq + q];
    M = fmaxf(M, mm[s]);
  }
  float denom = 0.f;
  float4v acc = {0.f, 0.f, 0.f, 0.f};
#pragma unroll
  for (int s = 0; s < 4; ++s) {
    const float ww = EXP2(mm[s] - M);
    denom += lv[s] * ww;
    const float* Ob = (s == 0) ? Op0 : (OpR + (size_t)(s - 1) * Nseq * 1024);
    float4v o = *(const float4v*)(Ob + (size_t)q * 1024 + c4);
    acc.x += o.x * ww; acc.y += o.y * ww; acc.z += o.z * ww; acc.w += o.w * ww;
  }
  const float inv = 1.f / denom;
  ushort4v r;
  r.x = f2bf(acc.x * inv);
  r.y = f2bf(acc.y * inv);
  r.z = f2bf(acc.z * inv);
  r.w = f2bf(acc.w * inv);
  *(ushort4v*)(out + (size_t)q * 1024 + c4) = r;
}

// ---------------------------------------------------------------------------
// Row LayerNorm (two-pass, fp32).  One block (256 thr) per row.
// ---------------------------------------------------------------------------
template <int D>
__global__ __launch_bounds__(256) void ln_rows(const float* __restrict__ src,
                                               const float* __restrict__ gw,
                                               const float* __restrict__ bw,
                                               float* __restrict__ outF,
                                               unsigned short* __restrict__ outB) {
  __shared__ float red[4];
  const int row = blockIdx.x;
  const int tid = threadIdx.x, w = tid >> 6;
  constexpr int PT = D / 256;
  const float* r = src + (size_t)row * D;
  float v[PT];
  float s = 0.f;
#pragma unroll
  for (int i = 0; i < PT; ++i) { v[i] = r[tid + i * 256]; s += v[i]; }
#pragma unroll
  for (int off = 32; off; off >>= 1) s += __shfl_down(s, off);
  if ((tid & 63) == 0) red[w] = s;
  __syncthreads();
  const float mean = (red[0] + red[1] + red[2] + red[3]) / D;
  __syncthreads();
  float q = 0.f;
#pragma unroll
  for (int i = 0; i < PT; ++i) { const float d = v[i] - mean; q += d * d; }
#pragma unroll
  for (int off = 32; off; off >>= 1) q += __shfl_down(q, off);
  if ((tid & 63) == 0) red[w] = q;
  __syncthreads();
  const float rstd = rsqrtf((red[0] + red[1] + red[2] + red[3]) / D + 1e-5f);
#pragma unroll
  for (int i = 0; i < PT; ++i) {
    const int c = tid + i * 256;
    const float o = (v[i] - mean) * rstd * gw[c] + bw[c];
    outF[(size_t)row * D + c] = o;
    if (outB) outB[(size_t)row * D + c] = f2bf(o);
  }
}

// ---------------------------------------------------------------------------
// Orchestration
// ---------------------------------------------------------------------------
extern "C" void kernel_launch(void* const* d_in, const int* in_sizes, int n_in,
                              void* d_out, int out_size, void* d_ws, size_t ws_size,
                              hipStream_t stream) {
  const int N = 2048, D_IN = 512, H = 1024, D_OUT = 256, NL = 4;
  const float* x    = (const float*)d_in[0];
  const float* W1   = (const float*)d_in[1];
  const float* b1   = (const float*)d_in[2];
  const float* Wqkv = (const float*)d_in[3];
  const float* bqkv = (const float*)d_in[4];
  const float* Wo   = (const float*)d_in[5];
  const float* bo   = (const float*)d_in[6];
  const float* lng  = (const float*)d_in[7];
  const float* lnb  = (const float*)d_in[8];
  const float* W2   = (const float*)d_in[9];
  const float* b2   = (const float*)d_in[10];
  const float* gout = (const float*)d_in[11];
  const float* bout = (const float*)d_in[12];
  float* out = (float*)d_out;

  char* ws = (char*)d_ws;
  auto alloc = [&](size_t bytes) -> char* {
    char* p = ws;
    ws += (bytes + 255) & ~(size_t)255;
    return p;
  };
  unsigned short* xb    = (unsigned short*)alloc((size_t)N * D_IN * 2);
  unsigned short* W1b   = (unsigned short*)alloc((size_t)H * D_IN * 2);
  unsigned short* Wqkvb = (unsigned short*)alloc((size_t)NL * 3 * H * H * 2);
  unsigned short* Wob   = (unsigned short*)alloc((size_t)NL * H * H * 2);
  unsigned short* W2b   = (unsigned short*)alloc((size_t)D_OUT * H * 2);
  unsigned short* hb    = (unsigned short*)alloc((size_t)N * H * 2);
  unsigned short* qkvb  = (unsigned short*)alloc((size_t)N * 3 * H * 2);
  unsigned short* aob   = (unsigned short*)alloc((size_t)N * H * 2);
  unsigned short* vtg   = (unsigned short*)alloc((size_t)H * N * 2);
  float* hf  = (float*)alloc((size_t)N * H * 4);
  float* af  = (float*)alloc((size_t)N * H * 4);   // aliased as attn partial Op0
  float* opR = (float*)alloc((size_t)3 * N * H * 4);
  float* ml  = (float*)alloc((size_t)4 * 16 * N * 4);
  float* ll  = (float*)alloc((size_t)4 * 16 * N * 4);
  float* yf  = (float*)alloc((size_t)N * D_OUT * 4);
  float* op0 = af;  // safe: combine consumes op0 before o-proj writes af

  // ---- fused bf16 conversion (1 launch for all 5 arrays)
  CvtArgs ca;
  ca.s[0] = x;    ca.d[0] = xb;
  ca.s[1] = W1;   ca.d[1] = W1b;
  ca.s[2] = Wqkv; ca.d[2] = Wqkvb;
  ca.s[3] = Wo;   ca.d[3] = Wob;
  ca.s[4] = W2;   ca.d[4] = W2b;
  const int n0 = N * D_IN, n1 = H * D_IN, n2 = NL * 3 * H * H, n3 = NL * H * H, n4 = D_OUT * H;
  ca.off[0] = 0;
  ca.off[1] = n0;
  ca.off[2] = n0 + n1;
  ca.off[3] = n0 + n1 + n2;
  ca.off[4] = n0 + n1 + n2 + n3;
  ca.off[5] = n0 + n1 + n2 + n3 + n4;
  const int ntot4 = ca.off[5] / 4;
  cvt_multi<<<2048, 256, 0, stream>>>(ca, ntot4);

  // FC1: h = relu(x @ W1^T + b1) -> hf, hb
  gemm_bt<true, false, true, true, false><<<dim3(H / 128, N / 128), 256, 0, stream>>>(
      xb, W1b, b1, nullptr, hf, hb, nullptr, 0, 0, N, H, D_IN);

  for (int l = 0; l < NL; ++l) {
    // qkv = h @ Wqkv^T + bqkv ; also emits V^T (cols >= 2048) into vtg
    gemm_bt<false, false, false, true, true><<<dim3(3 * H / 128, N / 128), 256, 0, stream>>>(
        hb, Wqkvb + (size_t)l * 3 * H * H, bqkv + (size_t)l * 3 * H, nullptr, nullptr, qkvb,
        vtg, 2 * H, N, N, 3 * H, H);
    flash_attn4<<<1024, 256, 0, stream>>>(qkvb, vtg, op0, opR, ml, ll, N);
    attn_combine4<<<(N * H / 4) / 256, 256, 0, stream>>>(op0, opR, ml, ll, aob, N);
    gemm_bt<false, true, true, false, false><<<dim3(H / 128, N / 128), 256, 0, stream>>>(
        aob, Wob + (size_t)l * H * H, bo + (size_t)l * H, hf, af, nullptr, nullptr, 0, 0,
        N, H, H);
    ln_rows<1024><<<N, 256, 0, stream>>>(af, lng + (size_t)l * H, lnb + (size_t)l * H, hf, hb);
  }

  gemm_bt<true, false, true, false, false><<<dim3(D_OUT / 128, N / 128), 256, 0, stream>>>(
      hb, W2b, b2, nullptr, yf, nullptr, nullptr, 0, 0, N, D_OUT, H);
  ln_rows<256><<<N, 256, 0, stream>>>(yf, gout, bout, out, nullptr);
}

// Round 6
// 416.977 us; speedup vs baseline: 1.8257x; 1.0153x over previous
//
#include <hip/hip_runtime.h>

// ---------------------------------------------------------------------------
// Types / helpers
// ---------------------------------------------------------------------------
typedef __attribute__((ext_vector_type(8))) short short8;      // 8 bf16
typedef __attribute__((ext_vector_type(4))) float f32x4;
typedef __attribute__((ext_vector_type(16))) float f32x16;     // 32x32 mfma acc
typedef __attribute__((ext_vector_type(4))) float float4v;
typedef __attribute__((ext_vector_type(4))) unsigned short ushort4v;
typedef __attribute__((ext_vector_type(4))) unsigned int uint4v;
typedef __attribute__((ext_vector_type(2))) unsigned int uint2v;

#define MFMA16(a, b, c) __builtin_amdgcn_mfma_f32_16x16x32_bf16((a), (b), (c), 0, 0, 0)
#define MFMA32(a, b, c) __builtin_amdgcn_mfma_f32_32x32x16_bf16((a), (b), (c), 0, 0, 0)
#define GLOAD_LDS16(g, s)                                                         \
  __builtin_amdgcn_global_load_lds((const __attribute__((address_space(1))) void*)(g), \
                                   (__attribute__((address_space(3))) void*)(s), 16, 0, 0)
#define EXP2(x) __builtin_amdgcn_exp2f(x)

__device__ __forceinline__ unsigned short f2bf(float f) {
  unsigned u = __builtin_bit_cast(unsigned, f);
  u += 0x7fffu + ((u >> 16) & 1u);   // round-to-nearest-even
  return (unsigned short)(u >> 16);
}

__device__ __forceinline__ unsigned cvtpk(float lo, float hi) {
  unsigned r;
  asm("v_cvt_pk_bf16_f32 %0, %1, %2" : "=v"(r) : "v"(lo), "v"(hi));
  return r;
}

// v_permlane32_swap_b32 a, b: a[32:63] <-> b[0:31]
__device__ __forceinline__ void swap32(unsigned& a, unsigned& b) {
  asm volatile("v_permlane32_swap_b32 %0, %1" : "+v"(a), "+v"(b));
}

__device__ __forceinline__ float bflo(unsigned u) {
  return __builtin_bit_cast(float, u << 16);
}
__device__ __forceinline__ float bfhi(unsigned u) {
  return __builtin_bit_cast(float, u & 0xffff0000u);
}

// ---------------------------------------------------------------------------
// Fused fp32 -> bf16 convert for all 5 weight/input arrays (1 launch)
// ---------------------------------------------------------------------------
struct CvtArgs {
  const float* s[5];
  unsigned short* d[5];
  int off[6];
};

__global__ __launch_bounds__(256) void cvt_multi(CvtArgs a, int ntot4) {
  int i4 = blockIdx.x * 256 + threadIdx.x;
  const int stride = gridDim.x * 256;
  for (; i4 < ntot4; i4 += stride) {
    const int idx = i4 * 4;
    int s = 0;
#pragma unroll
    for (int k = 0; k < 4; ++k) s += (idx >= a.off[k + 1]) ? 1 : 0;
    const int local = idx - a.off[s];
    float4v v = *(const float4v*)(a.s[s] + local);
    ushort4v o;
    o.x = f2bf(v.x); o.y = f2bf(v.y); o.z = f2bf(v.z); o.w = f2bf(v.w);
    *(ushort4v*)(a.d[s] + local) = o;
  }
}

// ---------------------------------------------------------------------------
// GEMM: C[M][N] = act(A[M][K] @ B[N][K]^T + bias[N]) (+ residual)
// BMxBN tile (4 waves, 2x2), BK=32, 2-phase dbuf, 1D grid + XCD swizzle.
// OUTT: also write C^T for cols >= tcol0 (V^T production).
// ---------------------------------------------------------------------------
template <int BM, int BN, bool RELU, bool RES, bool OUTF, bool OUTB, bool OUTT>
__global__ __launch_bounds__(256) void gemm_bt(const unsigned short* __restrict__ A,
                                               const unsigned short* __restrict__ B,
                                               const float* __restrict__ bias,
                                               const float* __restrict__ res,
                                               float* __restrict__ outF,
                                               unsigned short* __restrict__ outB,
                                               unsigned short* __restrict__ outT,
                                               int tcol0, int ldt,
                                               int M, int N, int K) {
  __shared__ __align__(16) unsigned short As[2][BM * 32];
  __shared__ __align__(16) unsigned short Bs[2][BN * 32];
  constexpr int MI = BM / 32, MJ = BN / 32, CA = BM / 64, CB = BN / 64;
  const int tid = threadIdx.x;
  const int w = tid >> 6, lane = tid & 63;
  const int l15 = lane & 15, l4 = lane >> 4;

  // 1D grid, bijective XCD swizzle (gridDim.x % 8 == 0)
  const int nwg = gridDim.x;
  const int wg = (blockIdx.x & 7) * (nwg >> 3) + (blockIdx.x >> 3);
  const int nbx = N / BN;
  const int rowBase = (wg / nbx) * BM;
  const int colBase = (wg % nbx) * BN;
  const int wm = w >> 1, wn = w & 1;

  f32x4 acc[MI][MJ] = {};

  auto stage = [&](int buf, int k0) {
#pragma unroll
    for (int i = 0; i < CA; ++i) {
      const int c = i * 256 + tid;
      GLOAD_LDS16(A + (size_t)(rowBase + (c >> 2)) * K + k0 + ((c & 3) << 3),
                  As[buf] + i * 2048 + w * 512);
    }
#pragma unroll
    for (int i = 0; i < CB; ++i) {
      const int c = i * 256 + tid;
      GLOAD_LDS16(B + (size_t)(colBase + (c >> 2)) * K + k0 + ((c & 3) << 3),
                  Bs[buf] + i * 2048 + w * 512);
    }
  };

  stage(0, 0);
  __syncthreads();

  int p = 0;
  for (int k0 = 0; k0 < K; k0 += 32) {
    if (k0 + 32 < K) stage(p ^ 1, k0 + 32);   // issue next tile early

    short8 af[MI], bf[MJ];
#pragma unroll
    for (int f = 0; f < MI; ++f)
      af[f] = *(const short8*)(As[p] + (wm * (BM / 2) + f * 16 + l15) * 32 + l4 * 8);
#pragma unroll
    for (int f = 0; f < MJ; ++f)
      bf[f] = *(const short8*)(Bs[p] + (wn * (BN / 2) + f * 16 + l15) * 32 + l4 * 8);
#pragma unroll
    for (int i = 0; i < MI; ++i)
#pragma unroll
      for (int j = 0; j < MJ; ++j)
        acc[i][j] = MFMA16(af[i], bf[j], acc[i][j]);

    __syncthreads();
    p ^= 1;
  }

#pragma unroll
  for (int i = 0; i < MI; ++i) {
    const int row0 = rowBase + wm * (BM / 2) + i * 16 + l4 * 4;
#pragma unroll
    for (int j = 0; j < MJ; ++j) {
      const int col = colBase + wn * (BN / 2) + j * 16 + l15;
      const float bv = bias[col];
      float vv[4];
#pragma unroll
      for (int e = 0; e < 4; ++e) {
        float v = acc[i][j][e] + bv;
        if constexpr (RELU) v = fmaxf(v, 0.f);
        if constexpr (RES) v += res[(size_t)(row0 + e) * N + col];
        vv[e] = v;
        if constexpr (OUTF) outF[(size_t)(row0 + e) * N + col] = v;
        if constexpr (OUTB) outB[(size_t)(row0 + e) * N + col] = f2bf(v);
      }
      if constexpr (OUTT) {
        if (col >= tcol0) {
          ushort4v t;
          t.x = f2bf(vv[0]); t.y = f2bf(vv[1]); t.z = f2bf(vv[2]); t.w = f2bf(vv[3]);
          *(ushort4v*)(outT + (size_t)(col - tcol0) * ldt + row0) = t;
        }
      }
    }
  }
}

// ---------------------------------------------------------------------------
// Flash attention v4: 32x32x16 MFMA, in-register softmax + P (cvt_pk +
// permlane32_swap), XOR-swizzled [64][64] K/Vt LDS tiles, dbuf staging,
// KSPLIT=4 over keys.  Partials stored bf16.
// ---------------------------------------------------------------------------
__global__ __launch_bounds__(256, 3) void flash_attn4(const unsigned short* __restrict__ qkv,
                                                      const unsigned short* __restrict__ vt,
                                                      unsigned short* __restrict__ Op0,
                                                      unsigned short* __restrict__ OpR,
                                                      float* __restrict__ Ml,
                                                      float* __restrict__ Ll,
                                                      int Nseq) {
  __shared__ __align__(16) unsigned short Ks[2][64 * 64];
  __shared__ __align__(16) unsigned short Vs[2][64 * 64];
  const int tid = threadIdx.x, w = tid >> 6, lane = tid & 63;
  const int l31 = lane & 31, l2h = lane >> 5, l7 = l31 & 7;
  const float CSC = 0.18033688011112042f;   // 0.125 * log2(e)

  const int b = blockIdx.x;
  const int head = (b & 7) * 2 + ((b >> 3) & 1);
  const int s = (b >> 4) & 3;
  const int qb = b >> 6;
  const int q0w = qb * 128 + w * 32;

  const unsigned short* Qp = qkv + head * 64;
  const unsigned short* Kp = qkv + 1024 + head * 64;
  const unsigned short* Vtp = vt + (size_t)head * 64 * Nseq;

  short8 qf[4];
#pragma unroll
  for (int ka = 0; ka < 4; ++ka)
    qf[ka] = *(const short8*)(Qp + (size_t)(q0w + l31) * 3072 + ka * 16 + l2h * 8);

  f32x16 OT0 = {}, OT1 = {};
  float m = -1e30f, ls = 0.f;

  const int sr = tid >> 3, su = tid & 7;
  const int sOffA = sr * 64 + ((su ^ (sr & 7)) * 8);
  const int sOffB = sOffA + 32 * 64;

  const int kt0 = s * (Nseq >> 2);
  const int NIT = Nseq >> 8;

  short8 k0 = *(const short8*)(Kp + (size_t)(kt0 + sr) * 3072 + su * 8);
  short8 k1 = *(const short8*)(Kp + (size_t)(kt0 + sr + 32) * 3072 + su * 8);
  short8 v0 = *(const short8*)(Vtp + (size_t)sr * Nseq + kt0 + su * 8);
  short8 v1 = *(const short8*)(Vtp + (size_t)(sr + 32) * Nseq + kt0 + su * 8);
  *(short8*)(Ks[0] + sOffA) = k0;
  *(short8*)(Ks[0] + sOffB) = k1;
  *(short8*)(Vs[0] + sOffA) = v0;
  *(short8*)(Vs[0] + sOffB) = v1;
  __syncthreads();

  int p = 0;
  for (int it = 0; it < NIT; ++it) {
    const bool more = (it + 1) < NIT;
    if (more) {   // issue next-tile loads early (T14)
      const int ktn = kt0 + (it + 1) * 64;
      k0 = *(const short8*)(Kp + (size_t)(ktn + sr) * 3072 + su * 8);
      k1 = *(const short8*)(Kp + (size_t)(ktn + sr + 32) * 3072 + su * 8);
      v0 = *(const short8*)(Vtp + (size_t)sr * Nseq + ktn + su * 8);
      v1 = *(const short8*)(Vtp + (size_t)(sr + 32) * Nseq + ktn + su * 8);
    }
    const unsigned short* KS = Ks[p];
    const unsigned short* VS = Vs[p];

    // ---- QK^T: S^T[key][q]
    f32x16 S0 = {}, S1 = {};
    __builtin_amdgcn_s_setprio(1);
#pragma unroll
    for (int ka = 0; ka < 4; ++ka) {
      const int un = ((ka * 2 + l2h) ^ l7) * 8;
      const short8 a0 = *(const short8*)(KS + l31 * 64 + un);
      const short8 a1 = *(const short8*)(KS + (32 + l31) * 64 + un);
      S0 = MFMA32(a0, qf[ka], S0);
      S1 = MFMA32(a1, qf[ka], S1);
    }
    __builtin_amdgcn_s_setprio(0);

    // ---- row max
    float pm = S0[0];
#pragma unroll
    for (int r = 1; r < 16; ++r) pm = fmaxf(pm, S0[r]);
#pragma unroll
    for (int r = 0; r < 16; ++r) pm = fmaxf(pm, S1[r]);
    pm = fmaxf(pm, __shfl_xor(pm, 32));
    pm *= CSC;

    // defer-max rescale
    if (__any(pm > m + 8.f)) {
      const float mn = fmaxf(m, pm);
      const float fac = EXP2(m - mn);
      m = mn;
      ls *= fac;
#pragma unroll
      for (int r = 0; r < 16; ++r) { OT0[r] *= fac; OT1[r] *= fac; }
    }

    // ---- P = exp2(S*CSC - m)
    float rs = 0.f;
    unsigned W0[4][2], W1[4][2];
#pragma unroll
    for (int g = 0; g < 4; ++g) {
      const float a0 = EXP2(fmaf(S0[4 * g + 0], CSC, -m));
      const float a1 = EXP2(fmaf(S0[4 * g + 1], CSC, -m));
      const float a2 = EXP2(fmaf(S0[4 * g + 2], CSC, -m));
      const float a3 = EXP2(fmaf(S0[4 * g + 3], CSC, -m));
      const float b0 = EXP2(fmaf(S1[4 * g + 0], CSC, -m));
      const float b1 = EXP2(fmaf(S1[4 * g + 1], CSC, -m));
      const float b2 = EXP2(fmaf(S1[4 * g + 2], CSC, -m));
      const float b3 = EXP2(fmaf(S1[4 * g + 3], CSC, -m));
      rs += ((a0 + a1) + (a2 + a3)) + ((b0 + b1) + (b2 + b3));
      W0[g][0] = cvtpk(a0, a1); W0[g][1] = cvtpk(a2, a3);
      W1[g][0] = cvtpk(b0, b1); W1[g][1] = cvtpk(b2, b3);
    }
    rs += __shfl_xor(rs, 32);
    ls += rs;

    // ---- exchange halves -> PV B-frags
    short8 pf[2][2];
#pragma unroll
    for (int ka = 0; ka < 2; ++ka) {
      {
        unsigned x0 = W0[2 * ka][0], y0 = W0[2 * ka + 1][0];
        unsigned x1 = W0[2 * ka][1], y1 = W0[2 * ka + 1][1];
        swap32(x0, y0);
        swap32(x1, y1);
        uint4v u = {x0, x1, y0, y1};
        pf[0][ka] = __builtin_bit_cast(short8, u);
      }
      {
        unsigned x0 = W1[2 * ka][0], y0 = W1[2 * ka + 1][0];
        unsigned x1 = W1[2 * ka][1], y1 = W1[2 * ka + 1][1];
        swap32(x0, y0);
        swap32(x1, y1);
        uint4v u = {x0, x1, y0, y1};
        pf[1][ka] = __builtin_bit_cast(short8, u);
      }
    }

    // ---- O^T += V^T x P^T
    __builtin_amdgcn_s_setprio(1);
#pragma unroll
    for (int sub = 0; sub < 2; ++sub)
#pragma unroll
      for (int ka = 0; ka < 2; ++ka) {
        const int un = ((sub * 4 + ka * 2 + l2h) ^ l7) * 8;
        const short8 va0 = *(const short8*)(VS + l31 * 64 + un);
        const short8 va1 = *(const short8*)(VS + (32 + l31) * 64 + un);
        OT0 = MFMA32(va0, pf[sub][ka], OT0);
        OT1 = MFMA32(va1, pf[sub][ka], OT1);
      }
    __builtin_amdgcn_s_setprio(0);

    if (more) {
      unsigned short* Kn = Ks[p ^ 1];
      unsigned short* Vn = Vs[p ^ 1];
      *(short8*)(Kn + sOffA) = k0;
      *(short8*)(Kn + sOffB) = k1;
      *(short8*)(Vn + sOffA) = v0;
      *(short8*)(Vn + sOffB) = v1;
    }
    __syncthreads();
    p ^= 1;
  }

  // ---- epilogue: bf16 un-normalized partials + (m, ls)
  unsigned short* Ob = (s == 0) ? Op0 : (OpR + (size_t)(s - 1) * Nseq * 1024);
  const int q = q0w + l31;
#pragma unroll
  for (int g = 0; g < 4; ++g) {
    const int d0 = 8 * g + 4 * l2h;
    uint2v t0 = {cvtpk(OT0[4 * g], OT0[4 * g + 1]), cvtpk(OT0[4 * g + 2], OT0[4 * g + 3])};
    uint2v t1 = {cvtpk(OT1[4 * g], OT1[4 * g + 1]), cvtpk(OT1[4 * g + 2], OT1[4 * g + 3])};
    *(uint2v*)(Ob + (size_t)q * 1024 + head * 64 + d0) = t0;
    *(uint2v*)(Ob + (size_t)q * 1024 + head * 64 + 32 + d0) = t1;
  }
  if (l2h == 0) {
    Ml[(size_t)(s * 16 + head) * Nseq + q] = m;
    Ll[(size_t)(s * 16 + head) * Nseq + q] = ls;
  }
}

// ---------------------------------------------------------------------------
// Combine the 4 key-split bf16 partials (exp2 domain) -> bf16 attention out
// ---------------------------------------------------------------------------
__global__ __launch_bounds__(256) void attn_combine4(const unsigned short* __restrict__ Op0,
                                                     const unsigned short* __restrict__ OpR,
                                                     const float* __restrict__ Ml,
                                                     const float* __restrict__ Ll,
                                                     unsigned short* __restrict__ out, int Nseq) {
  const int t = blockIdx.x * 256 + threadIdx.x;
  const int q = t >> 8, c4 = (t & 255) * 4;
  const int head = c4 >> 6;
  float mm[4], lv[4];
  float M = -1e30f;
#pragma unroll
  for (int s = 0; s < 4; ++s) {
    mm[s] = Ml[(size_t)(s * 16 + head) * Nseq + q];
    lv[s] = Ll[(size_t)(s * 16 + head) * Nseq + q];
    M = fmaxf(M, mm[s]);
  }
  float denom = 0.f;
  float4v acc = {0.f, 0.f, 0.f, 0.f};
#pragma unroll
  for (int s = 0; s < 4; ++s) {
    const float ww = EXP2(mm[s] - M);
    denom += lv[s] * ww;
    const unsigned short* Ob = (s == 0) ? Op0 : (OpR + (size_t)(s - 1) * Nseq * 1024);
    uint2v o = *(const uint2v*)(Ob + (size_t)q * 1024 + c4);
    acc.x += bflo(o.x) * ww;
    acc.y += bfhi(o.x) * ww;
    acc.z += bflo(o.y) * ww;
    acc.w += bfhi(o.y) * ww;
  }
  const float inv = 1.f / denom;
  ushort4v r;
  r.x = f2bf(acc.x * inv);
  r.y = f2bf(acc.y * inv);
  r.z = f2bf(acc.z * inv);
  r.w = f2bf(acc.w * inv);
  *(ushort4v*)(out + (size_t)q * 1024 + c4) = r;
}

// ---------------------------------------------------------------------------
// Row LayerNorm (two-pass, fp32).  One block (256 thr) per row.
// ---------------------------------------------------------------------------
template <int D>
__global__ __launch_bounds__(256) void ln_rows(const float* __restrict__ src,
                                               const float* __restrict__ gw,
                                               const float* __restrict__ bw,
                                               float* __restrict__ outF,
                                               unsigned short* __restrict__ outB) {
  __shared__ float red[4];
  const int row = blockIdx.x;
  const int tid = threadIdx.x, w = tid >> 6;
  constexpr int PT = D / 256;
  const float* r = src + (size_t)row * D;
  float v[PT];
  float s = 0.f;
#pragma unroll
  for (int i = 0; i < PT; ++i) { v[i] = r[tid + i * 256]; s += v[i]; }
#pragma unroll
  for (int off = 32; off; off >>= 1) s += __shfl_down(s, off);
  if ((tid & 63) == 0) red[w] = s;
  __syncthreads();
  const float mean = (red[0] + red[1] + red[2] + red[3]) / D;
  __syncthreads();
  float q = 0.f;
#pragma unroll
  for (int i = 0; i < PT; ++i) { const float d = v[i] - mean; q += d * d; }
#pragma unroll
  for (int off = 32; off; off >>= 1) q += __shfl_down(q, off);
  if ((tid & 63) == 0) red[w] = q;
  __syncthreads();
  const float rstd = rsqrtf((red[0] + red[1] + red[2] + red[3]) / D + 1e-5f);
#pragma unroll
  for (int i = 0; i < PT; ++i) {
    const int c = tid + i * 256;
    const float o = (v[i] - mean) * rstd * gw[c] + bw[c];
    outF[(size_t)row * D + c] = o;
    if (outB) outB[(size_t)row * D + c] = f2bf(o);
  }
}

// ---------------------------------------------------------------------------
// Orchestration
// ---------------------------------------------------------------------------
extern "C" void kernel_launch(void* const* d_in, const int* in_sizes, int n_in,
                              void* d_out, int out_size, void* d_ws, size_t ws_size,
                              hipStream_t stream) {
  const int N = 2048, D_IN = 512, H = 1024, D_OUT = 256, NL = 4;
  const float* x    = (const float*)d_in[0];
  const float* W1   = (const float*)d_in[1];
  const float* b1   = (const float*)d_in[2];
  const float* Wqkv = (const float*)d_in[3];
  const float* bqkv = (const float*)d_in[4];
  const float* Wo   = (const float*)d_in[5];
  const float* bo   = (const float*)d_in[6];
  const float* lng  = (const float*)d_in[7];
  const float* lnb  = (const float*)d_in[8];
  const float* W2   = (const float*)d_in[9];
  const float* b2   = (const float*)d_in[10];
  const float* gout = (const float*)d_in[11];
  const float* bout = (const float*)d_in[12];
  float* out = (float*)d_out;

  char* ws = (char*)d_ws;
  auto alloc = [&](size_t bytes) -> char* {
    char* p = ws;
    ws += (bytes + 255) & ~(size_t)255;
    return p;
  };
  unsigned short* xb    = (unsigned short*)alloc((size_t)N * D_IN * 2);
  unsigned short* W1b   = (unsigned short*)alloc((size_t)H * D_IN * 2);
  unsigned short* Wqkvb = (unsigned short*)alloc((size_t)NL * 3 * H * H * 2);
  unsigned short* Wob   = (unsigned short*)alloc((size_t)NL * H * H * 2);
  unsigned short* W2b   = (unsigned short*)alloc((size_t)D_OUT * H * 2);
  unsigned short* hb    = (unsigned short*)alloc((size_t)N * H * 2);
  unsigned short* qkvb  = (unsigned short*)alloc((size_t)N * 3 * H * 2);
  unsigned short* aob   = (unsigned short*)alloc((size_t)N * H * 2);
  unsigned short* vtg   = (unsigned short*)alloc((size_t)H * N * 2);
  unsigned short* opb0  = (unsigned short*)alloc((size_t)N * H * 2);
  unsigned short* opbR  = (unsigned short*)alloc((size_t)3 * N * H * 2);
  float* hf  = (float*)alloc((size_t)N * H * 4);
  float* af  = (float*)alloc((size_t)N * H * 4);
  float* ml  = (float*)alloc((size_t)4 * 16 * N * 4);
  float* ll  = (float*)alloc((size_t)4 * 16 * N * 4);
  float* yf  = (float*)alloc((size_t)N * D_OUT * 4);

  // ---- fused bf16 conversion (1 launch for all 5 arrays)
  CvtArgs ca;
  ca.s[0] = x;    ca.d[0] = xb;
  ca.s[1] = W1;   ca.d[1] = W1b;
  ca.s[2] = Wqkv; ca.d[2] = Wqkvb;
  ca.s[3] = Wo;   ca.d[3] = Wob;
  ca.s[4] = W2;   ca.d[4] = W2b;
  const int n0 = N * D_IN, n1 = H * D_IN, n2 = NL * 3 * H * H, n3 = NL * H * H, n4 = D_OUT * H;
  ca.off[0] = 0;
  ca.off[1] = n0;
  ca.off[2] = n0 + n1;
  ca.off[3] = n0 + n1 + n2;
  ca.off[4] = n0 + n1 + n2 + n3;
  ca.off[5] = n0 + n1 + n2 + n3 + n4;
  const int ntot4 = ca.off[5] / 4;
  cvt_multi<<<2048, 256, 0, stream>>>(ca, ntot4);

  // FC1: h = relu(x @ W1^T + b1) -> hf, hb   (grid 16*16 = 256 blocks)
  gemm_bt<128, 64, true, false, true, true, false><<<(N / 128) * (H / 64), 256, 0, stream>>>(
      xb, W1b, b1, nullptr, hf, hb, nullptr, 0, 0, N, H, D_IN);

  for (int l = 0; l < NL; ++l) {
    // qkv = h @ Wqkv^T + bqkv ; also emits V^T (cols >= 2048)  (384 blocks)
    gemm_bt<128, 128, false, false, false, true, true><<<(N / 128) * (3 * H / 128), 256, 0, stream>>>(
        hb, Wqkvb + (size_t)l * 3 * H * H, bqkv + (size_t)l * 3 * H, nullptr, nullptr, qkvb,
        vtg, 2 * H, N, N, 3 * H, H);
    flash_attn4<<<1024, 256, 0, stream>>>(qkvb, vtg, opb0, opbR, ml, ll, N);
    attn_combine4<<<(N * H / 4) / 256, 256, 0, stream>>>(opb0, opbR, ml, ll, aob, N);
    // o-proj + residual  (256 blocks)
    gemm_bt<128, 64, false, true, true, false, false><<<(N / 128) * (H / 64), 256, 0, stream>>>(
        aob, Wob + (size_t)l * H * H, bo + (size_t)l * H, hf, af, nullptr, nullptr, 0, 0,
        N, H, H);
    ln_rows<1024><<<N, 256, 0, stream>>>(af, lng + (size_t)l * H, lnb + (size_t)l * H, hf, hb);
  }

  // FC2 (128 blocks of 64x64)
  gemm_bt<64, 64, true, false, true, false, false><<<(N / 64) * (D_OUT / 64), 256, 0, stream>>>(
      hb, W2b, b2, nullptr, yf, nullptr, nullptr, 0, 0, N, D_OUT, H);
  ln_rows<256><<<N, 256, 0, stream>>>(yf, gout, bout, out, nullptr);
}